// Round 18
// baseline (1303.384 us; speedup 1.0000x reference)
//
#include <hip/hip_runtime.h>

#define HH 128
#define EAA 16
#define NNODES 100000
#define NEDGES 500000
#define NBATCH (NEDGES / 16)   // 31250 exact
#define NNB    (NNODES / 16)   // 6250 exact
#define CHUNK 512
#define NCHUNK ((NNODES + CHUNK - 1) / CHUNK)  // 196

// global transposed-weight row strides (elements, 16B-multiple)
#define GE1 160   // edge w1t: k in [0,160), real 144, pad zeroed
#define GE2 128
#define GN1 256
#define GN2 128
#define NW 8      // waves per block
#define LROW 136  // src-rows LDS stride in u16 (272 B)
#define LROWM 140 // msg-tile LDS stride in u16 (280 B)
#define OTS 36    // node out-tile stride in f32 (144 B, 16B-aligned)

typedef unsigned int u32;
typedef unsigned short u16;
typedef __attribute__((ext_vector_type(8))) short bf16x8;
typedef __attribute__((ext_vector_type(4))) short s16x4;
typedef __attribute__((ext_vector_type(4))) float f32x4;

__device__ __forceinline__ float bf_lo(u32 v){ return __builtin_bit_cast(float, (u32)(v << 16)); }
__device__ __forceinline__ float bf_hi(u32 v){ return __builtin_bit_cast(float, (u32)(v & 0xffff0000u)); }
__device__ __forceinline__ u16 f2bf(float f){
  u32 x = __builtin_bit_cast(u32, f);
  return (u16)((x + 0x7fffu + ((x >> 16) & 1u)) >> 16);
}
__device__ __forceinline__ float sigm(float x){ return 1.0f / (1.0f + __expf(-x)); }
__device__ __forceinline__ uint2 shfl64(uint2 v, int src){
  uint2 r;
  r.x = (u32)__shfl((int)v.x, src, 64);
  r.y = (u32)__shfl((int)v.y, src, 64);
  return r;
}
__device__ __forceinline__ bf16x8 ld8f_bf(const float* p){
  float4 v0 = *(const float4*)(p);
  float4 v1 = *(const float4*)(p + 4);
  uint4 u;
  u.x = ((u32)f2bf(v0.y) << 16) | f2bf(v0.x);
  u.y = ((u32)f2bf(v0.w) << 16) | f2bf(v0.z);
  u.z = ((u32)f2bf(v1.y) << 16) | f2bf(v1.x);
  u.w = ((u32)f2bf(v1.w) << 16) | f2bf(v1.z);
  return __builtin_bit_cast(bf16x8, u);
}

// ===========================================================================
// Weight staging: transpose f32 [K][128] -> bf16 [128][Kpad] (zero pad).
// ===========================================================================
__global__ void stage_weights(
    const float* __restrict__ w1e, const float* __restrict__ w2e, const float* __restrict__ mwe,
    const float* __restrict__ w1n, const float* __restrict__ w2n,
    u16* __restrict__ gw1e, u16* __restrict__ gw2e, u16* __restrict__ gmwe,
    u16* __restrict__ gw1n, u16* __restrict__ gw2n)
{
  const float* src; u16* dst; int K, KP;
  switch (blockIdx.y) {
    case 0: src = w1e; dst = gw1e; K = 144; KP = GE1; break;
    case 1: src = w2e; dst = gw2e; K = 128; KP = GE2; break;
    case 2: src = mwe; dst = gmwe; K = 128; KP = GE2; break;
    case 3: src = w1n; dst = gw1n; K = 256; KP = GN1; break;
    default: src = w2n; dst = gw2n; K = 128; KP = GN2; break;
  }
  int total = 128 * KP;
  for (int i = blockIdx.x * blockDim.x + threadIdx.x; i < total; i += gridDim.x * blockDim.x) {
    int f = i / KP, k = i - f * KP;
    dst[i] = (k < K) ? f2bf(src[(size_t)k * 128 + f]) : (u16)0;
  }
}

// ===========================================================================
// CSR build (both directions fused): count -> scan -> fill.
// fill also writes packed per-slot descriptors:
//   pairA[pa] = {src=p.y (hidden), dstSlot=pb, eid}  (phase-2 iteration order)
//   pairB[pb] = {src=p.x (clue),   dstSlot=pa, eid}  (phase-1 iteration order)
// One int4 load replaces the elist->edges/dstpos dependent chain.
// ===========================================================================
__global__ void count2_k(const int* __restrict__ edges,
                         int* __restrict__ cntA, int* __restrict__ cntB){
  int e = blockIdx.x * blockDim.x + threadIdx.x;
  if (e < NEDGES){
    int2 p = ((const int2*)edges)[e];
    atomicAdd(&cntA[p.y], 1);
    atomicAdd(&cntB[p.x], 1);
  }
}
__global__ void scanA2_k(const int* __restrict__ cntA, const int* __restrict__ cntB,
                         int* __restrict__ offA, int* __restrict__ offB,
                         int* __restrict__ csumA, int* __restrict__ csumB){
  const int* cnt = blockIdx.y ? cntB : cntA;
  int* off  = blockIdx.y ? offB : offA;
  int* csum = blockIdx.y ? csumB : csumA;
  __shared__ int ws[8];
  int i = blockIdx.x * CHUNK + threadIdx.x;
  int v = (i < NNODES) ? cnt[i] : 0;
  int lane = threadIdx.x & 63, w = threadIdx.x >> 6;
  int s = v;
#pragma unroll
  for (int d = 1; d < 64; d <<= 1){ int t = __shfl_up(s, d, 64); if (lane >= d) s += t; }
  if (lane == 63) ws[w] = s;
  __syncthreads();
  if (threadIdx.x == 0){
    int a = 0;
    for (int k = 0; k < 8; k++){ int t = ws[k]; ws[k] = a; a += t; }
    csum[blockIdx.x] = a;
  }
  __syncthreads();
  if (i < NNODES) off[i] = (s - v) + ws[w];
}
__global__ void scanB2_k(int* __restrict__ csumA, int* __restrict__ csumB){
  int lane = threadIdx.x & 63;
  for (int which = 0; which < 2; which++){
    int* c = which ? csumB : csumA;
    int carry = 0;
    for (int base = 0; base < NCHUNK; base += 64){
      int idx = base + lane;
      int v = (idx < NCHUNK) ? c[idx] : 0;
      int s = v;
#pragma unroll
      for (int d = 1; d < 64; d <<= 1){ int t = __shfl_up(s, d, 64); if (lane >= d) s += t; }
      if (idx < NCHUNK) c[idx] = s - v + carry;
      carry += __shfl(s, 63, 64);
    }
  }
}
__global__ void scanC2_k(int* __restrict__ offA, int* __restrict__ offB,
                         int* __restrict__ posA, int* __restrict__ posB,
                         const int* __restrict__ csumA, const int* __restrict__ csumB){
  int* off = blockIdx.y ? offB : offA;
  int* pos = blockIdx.y ? posB : posA;
  const int* csum = blockIdx.y ? csumB : csumA;
  int i = blockIdx.x * blockDim.x + threadIdx.x;
  if (i < NNODES){ int v = off[i] + csum[i / CHUNK]; off[i] = v; pos[i] = v; }
  if (i == 0) off[NNODES] = NEDGES;
}
__global__ void fill2_k(const int* __restrict__ edges,
                        int* __restrict__ posA, int* __restrict__ posB,
                        int4* __restrict__ pairA, int4* __restrict__ pairB){
  int e = blockIdx.x * blockDim.x + threadIdx.x;
  if (e < NEDGES){
    int2 p = ((const int2*)edges)[e];
    int pa = atomicAdd(&posA[p.y], 1);
    int pb = atomicAdd(&posB[p.x], 1);
    pairA[pa] = make_int4(p.y, pb, e, 0);   // phase 2: src = hidden (col 1)
    pairB[pb] = make_int4(p.x, pa, e, 0);   // phase 1: src = clue (col 0)
  }
}

// ===========================================================================
// Edge message kernel — r15/r17 verified body; the 3-load index chain is
// replaced by ONE int4 descriptor load per edge: {src, dstSlot, eid}.
// SRC-sorted iteration order (descriptor array is built in that order).
// ===========================================================================
__global__ __launch_bounds__(512, 2) void edge_msg_w(
    const float* __restrict__ srcN,
    const int4* __restrict__ pair,
    const float* __restrict__ eattr,
    const u16* __restrict__ w1t, const float* __restrict__ b1,
    const u16* __restrict__ w2t, const float* __restrict__ b2,
    const u16* __restrict__ mwt, const float* __restrict__ mb,
    u16* __restrict__ msgs)
{
  __shared__ float b1s[HH], b2s[HH], mbs[HH];
  __shared__ alignas(16) u16 rows[NW][16 * LROW];    // 34816 B
  __shared__ alignas(16) u16 msgt[NW][16 * LROWM];   // 35840 B
  const int tid = threadIdx.x;
  if (tid < HH){ b1s[tid] = b1[tid]; b2s[tid] = b2[tid]; mbs[tid] = mb[tid]; }
  __syncthreads();

  const int lane = tid & 63;
  const int wid  = tid >> 6;
  const int q    = lane >> 4;
  const int er   = lane & 15;
  const int ll   = lane & 31;    // row-load lane
  const int half = lane >> 5;    // which of the 2 rows this half-wave loads
  const int gw   = blockIdx.x * NW + wid;
  const int nwv  = gridDim.x * NW;
  const int srcA = 2 * (q & 1) * 16 + er;
  const int srcB = srcA + 16;
  const bool hiT = (q >> 1) != 0;
  u16* myrows = rows[wid];
  u16* mymsg  = msgt[wid];

  for (int b = gw; b < NBATCH; b += nwv) {
    const int e0 = b * 16;
    // single independent descriptor load: {src, dstSlot, eid}
    int4 pr = pair[e0 + er];
    const int s   = pr.x;
    const int dp  = pr.y;
    const int eid = pr.z;

    // ---- coalesced gather: half-wave loads one full 512-B row, bf16 -> LDS
#pragma unroll
    for (int p = 0; p < 8; p++) {
      int j = 2 * p + half;
      int sj = __shfl(s, j, 64);
      float4 v = *(const float4*)(srcN + (size_t)sj * HH + ll * 4);
      uint2 pk;
      pk.x = ((u32)f2bf(v.y) << 16) | f2bf(v.x);
      pk.y = ((u32)f2bf(v.w) << 16) | f2bf(v.z);
      *(s16x4*)(myrows + j * LROW + ll * 4) = __builtin_bit_cast(s16x4, pk);
    }
    asm volatile("" ::: "memory");   // order ds_writes before ds_reads

    // ---- B-frags from LDS + eattr tail
    bf16x8 bs[5];
#pragma unroll
    for (int kt = 0; kt < 4; kt++)
      bs[kt] = *(const bf16x8*)(myrows + er * LROW + kt * 32 + q * 8);
    if (q < 2) bs[4] = ld8f_bf(eattr + (size_t)eid * EAA + q * 8);
    else       bs[4] = (bf16x8){0,0,0,0,0,0,0,0};

    // ---- stage 1: y^T + SiLU
    uint2 pku[8];
#pragma unroll
    for (int t = 0; t < 8; t++) {
      const u16* ap = w1t + (size_t)(t * 16 + er) * GE1 + q * 8;
      f32x4 acc = {b1s[t*16 + q*4 + 0], b1s[t*16 + q*4 + 1],
                   b1s[t*16 + q*4 + 2], b1s[t*16 + q*4 + 3]};
#pragma unroll
      for (int kt = 0; kt < 5; kt++) {
        bf16x8 af = *(const bf16x8*)(ap + kt * 32);
        acc = __builtin_amdgcn_mfma_f32_16x16x32_bf16(af, bs[kt], acc, 0, 0, 0);
      }
      float v0 = acc[0] * sigm(acc[0]), v1 = acc[1] * sigm(acc[1]);
      float v2 = acc[2] * sigm(acc[2]), v3 = acc[3] * sigm(acc[3]);
      pku[t].x = ((u32)f2bf(v1) << 16) | f2bf(v0);
      pku[t].y = ((u32)f2bf(v3) << 16) | f2bf(v2);
    }

    // ---- D-layout -> B-frag redistribution (in-register)
    bf16x8 yb[4];
#pragma unroll
    for (int kt = 0; kt < 4; kt++) {
      uint2 aLo = shfl64(pku[2*kt],     srcA);
      uint2 aHi = shfl64(pku[2*kt + 1], srcA);
      uint2 bLo = shfl64(pku[2*kt],     srcB);
      uint2 bHi = shfl64(pku[2*kt + 1], srcB);
      uint4 w;
      w.x = hiT ? aHi.x : aLo.x;
      w.y = hiT ? aHi.y : aLo.y;
      w.z = hiT ? bHi.x : bLo.x;
      w.w = hiT ? bHi.y : bLo.y;
      yb[kt] = __builtin_bit_cast(bf16x8, w);
    }

    // ---- stage 2+3: gate & message -> LDS msg tile
#pragma unroll
    for (int t = 0; t < 8; t++) {
      const u16* ap2 = w2t + (size_t)(t * 16 + er) * GE2 + q * 8;
      const u16* ap3 = mwt + (size_t)(t * 16 + er) * GE2 + q * 8;
      f32x4 g = {b2s[t*16 + q*4 + 0], b2s[t*16 + q*4 + 1],
                 b2s[t*16 + q*4 + 2], b2s[t*16 + q*4 + 3]};
      f32x4 m = {mbs[t*16 + q*4 + 0], mbs[t*16 + q*4 + 1],
                 mbs[t*16 + q*4 + 2], mbs[t*16 + q*4 + 3]};
#pragma unroll
      for (int kt = 0; kt < 4; kt++) {
        bf16x8 a2 = *(const bf16x8*)(ap2 + kt * 32);
        g = __builtin_amdgcn_mfma_f32_16x16x32_bf16(a2, yb[kt], g, 0, 0, 0);
        bf16x8 a3 = *(const bf16x8*)(ap3 + kt * 32);
        m = __builtin_amdgcn_mfma_f32_16x16x32_bf16(a3, bs[kt], m, 0, 0, 0);
      }
      float v0 = m[0] * sigm(g[0]), v1 = m[1] * sigm(g[1]);
      float v2 = m[2] * sigm(g[2]), v3 = m[3] * sigm(g[3]);
      uint2 pk;
      pk.x = ((u32)f2bf(v1) << 16) | f2bf(v0);
      pk.y = ((u32)f2bf(v3) << 16) | f2bf(v2);
      *(s16x4*)(mymsg + er * LROWM + t * 16 + q * 4) = __builtin_bit_cast(s16x4, pk);
    }
    asm volatile("" ::: "memory");

    // ---- scatter store: quarter-wave per edge, 256 B = 2 full lines
#pragma unroll
    for (int p = 0; p < 4; p++) {
      int e_r = 4 * p + q;
      int dslot = __shfl(dp, e_r, 64);
      bf16x8 v = *(const bf16x8*)(mymsg + e_r * LROWM + er * 8);
      *(bf16x8*)(msgs + (size_t)dslot * 128 + er * 8) = v;
    }
  }
}

// ===========================================================================
// Node update — ROUND-16/17 VERIFIED FORM: CSR pull-aggregation + FULL-LINE
// out stores via per-wave LDS transpose tile.
// ===========================================================================
__global__ __launch_bounds__(512, 2) void node_csr(
    const float* __restrict__ hin,
    const u16* __restrict__ msgs, const int* __restrict__ off,
    const u16* __restrict__ w1t, const float* __restrict__ b1,
    const u16* __restrict__ w2t, const float* __restrict__ b2,
    const float* __restrict__ lng, const float* __restrict__ lnb,
    float* __restrict__ out)
{
  __shared__ float b1s[HH], b2s[HH], gsv[HH], bsv[HH];
  __shared__ alignas(16) float otile[NW][16 * OTS];   // 18432 B
  const int tid = threadIdx.x;
  if (tid < HH){ b1s[tid] = b1[tid]; b2s[tid] = b2[tid];
                 gsv[tid] = lng[tid]; bsv[tid] = lnb[tid]; }
  __syncthreads();

  const int lane = tid & 63;
  const int wid  = tid >> 6;
  const int q    = lane >> 4;
  const int nr   = lane & 15;
  const int gw   = blockIdx.x * NW + wid;
  const int nwv  = gridDim.x * NW;
  const int srcA = 2 * (q & 1) * 16 + nr;
  const int srcB = srcA + 16;
  const bool hiT = (q >> 1) != 0;
  float* myot = otile[wid];

  for (int nb = gw; nb < NNB; nb += nwv) {
    const int n = nb * 16 + nr;
    const size_t base = (size_t)n * HH;

    // ---- pull-aggregate: contiguous CSR slots of this node
    float av[32];
#pragma unroll
    for (int j = 0; j < 32; j++) av[j] = 0.0f;
    const int beg = off[n], end = off[n + 1];
    for (int i = 0; ; i++) {
      bool act = (beg + i < end);
      if (!__any(act)) break;
      if (act) {
        const u16* mp = msgs + (size_t)(beg + i) * 128 + q * 8;
#pragma unroll
        for (int kt = 0; kt < 4; kt++) {
          uint4 r = *(const uint4*)(mp + kt * 32);
          av[kt*8+0] += bf_lo(r.x); av[kt*8+1] += bf_hi(r.x);
          av[kt*8+2] += bf_lo(r.y); av[kt*8+3] += bf_hi(r.y);
          av[kt*8+4] += bf_lo(r.z); av[kt*8+5] += bf_hi(r.z);
          av[kt*8+6] += bf_lo(r.w); av[kt*8+7] += bf_hi(r.w);
        }
      }
    }

    // ---- B-frags: cat = [hin | agg]
    bf16x8 cb[8];
    const float* hp = hin + base + q * 8;
    cb[0] = ld8f_bf(hp);
    cb[1] = ld8f_bf(hp + 32);
    cb[2] = ld8f_bf(hp + 64);
    cb[3] = ld8f_bf(hp + 96);
#pragma unroll
    for (int kt = 0; kt < 4; kt++) {
      uint4 u;
      u.x = ((u32)f2bf(av[kt*8+1]) << 16) | f2bf(av[kt*8+0]);
      u.y = ((u32)f2bf(av[kt*8+3]) << 16) | f2bf(av[kt*8+2]);
      u.z = ((u32)f2bf(av[kt*8+5]) << 16) | f2bf(av[kt*8+4]);
      u.w = ((u32)f2bf(av[kt*8+7]) << 16) | f2bf(av[kt*8+6]);
      cb[4 + kt] = __builtin_bit_cast(bf16x8, u);
    }

    // ---- stage 1: u^T = relu(w1^T @ cat^T + b1)
    uint2 pku[8];
#pragma unroll
    for (int t = 0; t < 8; t++) {
      const u16* a1p = w1t + (size_t)(t * 16 + nr) * GN1 + q * 8;
      f32x4 acc = {b1s[t*16 + q*4 + 0], b1s[t*16 + q*4 + 1],
                   b1s[t*16 + q*4 + 2], b1s[t*16 + q*4 + 3]};
#pragma unroll
      for (int kt = 0; kt < 8; kt++) {
        bf16x8 af = *(const bf16x8*)(a1p + kt * 32);
        acc = __builtin_amdgcn_mfma_f32_16x16x32_bf16(af, cb[kt], acc, 0, 0, 0);
      }
      float v0 = fmaxf(acc[0], 0.0f), v1 = fmaxf(acc[1], 0.0f);
      float v2 = fmaxf(acc[2], 0.0f), v3 = fmaxf(acc[3], 0.0f);
      pku[t].x = ((u32)f2bf(v1) << 16) | f2bf(v0);
      pku[t].y = ((u32)f2bf(v3) << 16) | f2bf(v2);
    }

    bf16x8 yb[4];
#pragma unroll
    for (int kt = 0; kt < 4; kt++) {
      uint2 aLo = shfl64(pku[2*kt],     srcA);
      uint2 aHi = shfl64(pku[2*kt + 1], srcA);
      uint2 bLo = shfl64(pku[2*kt],     srcB);
      uint2 bHi = shfl64(pku[2*kt + 1], srcB);
      uint4 w;
      w.x = hiT ? aHi.x : aLo.x;
      w.y = hiT ? aHi.y : aLo.y;
      w.z = hiT ? bHi.x : bLo.x;
      w.w = hiT ? bHi.y : bLo.y;
      yb[kt] = __builtin_bit_cast(bf16x8, w);
    }

    // ---- stage 2 + residual + LN
    float xv[8][4];
    float psum = 0.0f;
#pragma unroll
    for (int t = 0; t < 8; t++) {
      const u16* a2p = w2t + (size_t)(t * 16 + nr) * GN2 + q * 8;
      f32x4 uacc = {b2s[t*16 + q*4 + 0], b2s[t*16 + q*4 + 1],
                    b2s[t*16 + q*4 + 2], b2s[t*16 + q*4 + 3]};
#pragma unroll
      for (int kt = 0; kt < 4; kt++) {
        bf16x8 a2 = *(const bf16x8*)(a2p + kt * 32);
        uacc = __builtin_amdgcn_mfma_f32_16x16x32_bf16(a2, yb[kt], uacc, 0, 0, 0);
      }
      float4 hv = *(const float4*)(hin + base + t * 16 + q * 4);
      xv[t][0] = hv.x + uacc[0];
      xv[t][1] = hv.y + uacc[1];
      xv[t][2] = hv.z + uacc[2];
      xv[t][3] = hv.w + uacc[3];
      psum += xv[t][0] + xv[t][1] + xv[t][2] + xv[t][3];
    }
    psum += __shfl_xor(psum, 16, 64);
    psum += __shfl_xor(psum, 32, 64);
    float mu = psum * (1.0f / 128.0f);
    float pvar = 0.0f;
#pragma unroll
    for (int t = 0; t < 8; t++) {
#pragma unroll
      for (int j = 0; j < 4; j++) {
        float dx = xv[t][j] - mu;
        xv[t][j] = dx;
        pvar += dx * dx;
      }
    }
    pvar += __shfl_xor(pvar, 16, 64);
    pvar += __shfl_xor(pvar, 32, 64);
    float inv = rsqrtf(pvar * (1.0f / 128.0f) + 1e-5f);
#pragma unroll
    for (int t = 0; t < 8; t++) {
      int F = t * 16 + q * 4;
      xv[t][0] = xv[t][0] * inv * gsv[F + 0] + bsv[F + 0];
      xv[t][1] = xv[t][1] * inv * gsv[F + 1] + bsv[F + 1];
      xv[t][2] = xv[t][2] * inv * gsv[F + 2] + bsv[F + 2];
      xv[t][3] = xv[t][3] * inv * gsv[F + 3] + bsv[F + 3];
    }

    // ---- full-line out stores via LDS transpose tile.
#pragma unroll
    for (int tp = 0; tp < 4; tp++) {
      asm volatile("" ::: "memory");   // previous tp's reads before overwrite
#pragma unroll
      for (int dt = 0; dt < 2; dt++) {
        int t = 2 * tp + dt;
        float4 v; v.x = xv[t][0]; v.y = xv[t][1]; v.z = xv[t][2]; v.w = xv[t][3];
        *(float4*)(myot + nr * OTS + dt * 16 + q * 4) = v;
      }
      asm volatile("" ::: "memory");
#pragma unroll
      for (int hf = 0; hf < 2; hf++) {
        int n8 = hf * 8 + (lane >> 3);
        int f  = (lane & 7) * 4;
        float4 v = *(const float4*)(myot + n8 * OTS + f);
        *(float4*)(out + (size_t)(nb * 16 + n8) * HH + tp * 32 + f) = v;
      }
    }
  }
}

// ===========================================================================
extern "C" void kernel_launch(void* const* d_in, const int* in_sizes, int n_in,
                              void* d_out, int out_size, void* d_ws, size_t ws_size,
                              hipStream_t stream) {
  const float* h_hidden = (const float*)d_in[0];
  const float* h_clue   = (const float*)d_in[1];
  const int*   edges    = (const int*)d_in[2];
  const float* eattr    = (const float*)d_in[3];
  const float* c2h_g_w1 = (const float*)d_in[4];  const float* c2h_g_b1 = (const float*)d_in[5];
  const float* c2h_g_w2 = (const float*)d_in[6];  const float* c2h_g_b2 = (const float*)d_in[7];
  const float* c2h_m_w  = (const float*)d_in[8];  const float* c2h_m_b  = (const float*)d_in[9];
  const float* h_u_w1   = (const float*)d_in[10]; const float* h_u_b1   = (const float*)d_in[11];
  const float* h_u_w2   = (const float*)d_in[12]; const float* h_u_b2   = (const float*)d_in[13];
  const float* h_ln_g   = (const float*)d_in[14]; const float* h_ln_b   = (const float*)d_in[15];
  const float* h2c_g_w1 = (const float*)d_in[16]; const float* h2c_g_b1 = (const float*)d_in[17];
  const float* h2c_g_w2 = (const float*)d_in[18]; const float* h2c_g_b2 = (const float*)d_in[19];
  const float* h2c_m_w  = (const float*)d_in[20]; const float* h2c_m_b  = (const float*)d_in[21];
  const float* c_u_w1   = (const float*)d_in[22]; const float* c_u_b1   = (const float*)d_in[23];
  const float* c_u_w2   = (const float*)d_in[24]; const float* c_u_b2   = (const float*)d_in[25];
  const float* c_ln_g   = (const float*)d_in[26]; const float* c_ln_b   = (const float*)d_in[27];

  float* out_hidden = (float*)d_out;
  float* out_clue   = (float*)d_out + (size_t)NNODES * HH;

  // ---- workspace carve-up
  char* W = (char*)d_ws;
  size_t woff = 0;
  auto take = [&](size_t nbytes) -> char* {
    char* p = W + woff;
    woff += (nbytes + 255) & ~(size_t)255;
    return p;
  };
  u16*  msgs  = (u16*)take((size_t)NEDGES * HH * 2);       // 128 MB
  int*  cntA  = (int*)take((size_t)NNODES * 2 * 4);        // contiguous pair
  int*  cntB  = cntA + NNODES;
  int*  offA  = (int*)take((size_t)(NNODES + 1) * 4);
  int*  offB  = (int*)take((size_t)(NNODES + 1) * 4);
  int*  posA  = (int*)take((size_t)NNODES * 4);
  int*  posB  = (int*)take((size_t)NNODES * 4);
  int4* pairA = (int4*)take((size_t)NEDGES * 16);          // 8 MB
  int4* pairB = (int4*)take((size_t)NEDGES * 16);          // 8 MB
  int*  csumA = (int*)take((size_t)NCHUNK * 4);
  int*  csumB = (int*)take((size_t)NCHUNK * 4);
  u16* gw1eA  = (u16*)take(128 * GE1 * 2);
  u16* gw2eA  = (u16*)take(128 * GE2 * 2);
  u16* gmweA  = (u16*)take(128 * GE2 * 2);
  u16* gw1nA  = (u16*)take(128 * GN1 * 2);
  u16* gw2nA  = (u16*)take(128 * GN2 * 2);
  u16* gw1eB  = (u16*)take(128 * GE1 * 2);
  u16* gw2eB  = (u16*)take(128 * GE2 * 2);
  u16* gmweB  = (u16*)take(128 * GE2 * 2);
  u16* gw1nB  = (u16*)take(128 * GN1 * 2);
  u16* gw2nB  = (u16*)take(128 * GN2 * 2);

  const int EB = (NEDGES + 255) / 256;
  const int NB = (NNODES + 255) / 256;

  // stage all weights (bf16, transposed)
  stage_weights<<<dim3(16, 5), 256, 0, stream>>>(
      c2h_g_w1, c2h_g_w2, c2h_m_w, h_u_w1, h_u_w2,
      gw1eA, gw2eA, gmweA, gw1nA, gw2nA);
  stage_weights<<<dim3(16, 5), 256, 0, stream>>>(
      h2c_g_w1, h2c_g_w2, h2c_m_w, c_u_w1, c_u_w2,
      gw1eB, gw2eB, gmweB, gw1nB, gw2nB);

  // CSR build (both directions, fused; fill writes packed descriptors)
  hipMemsetAsync(cntA, 0, (size_t)NNODES * 2 * 4, stream);
  count2_k<<<EB, 256, 0, stream>>>(edges, cntA, cntB);
  scanA2_k<<<dim3(NCHUNK, 2), CHUNK, 0, stream>>>(cntA, cntB, offA, offB, csumA, csumB);
  scanB2_k<<<1, 64, 0, stream>>>(csumA, csumB);
  scanC2_k<<<dim3(NB, 2), 256, 0, stream>>>(offA, offB, posA, posB, csumA, csumB);
  fill2_k<<<EB, 256, 0, stream>>>(edges, posA, posB, pairA, pairB);

  // Phase 1: clue -> hidden. pairB is src(clue)-sorted; dstSlot -> CSR-A.
  edge_msg_w<<<1024, 512, 0, stream>>>(h_clue, pairB, eattr,
      gw1eA, c2h_g_b1, gw2eA, c2h_g_b2, gmweA, c2h_m_b, msgs);
  node_csr<<<512, 512, 0, stream>>>(h_hidden, msgs, offA,
      gw1nA, h_u_b1, gw2nA, h_u_b2, h_ln_g, h_ln_b, out_hidden);

  // Phase 2: hidden_new -> clue. pairA is src(hidden)-sorted; dstSlot -> CSR-B.
  edge_msg_w<<<1024, 512, 0, stream>>>(out_hidden, pairA, eattr,
      gw1eB, h2c_g_b1, gw2eB, h2c_g_b2, gmweB, h2c_m_b, msgs);
  node_csr<<<512, 512, 0, stream>>>(h_clue, msgs, offB,
      gw1nB, c_u_b1, gw2nB, c_u_b2, c_ln_g, c_ln_b, out_clue);
}

// Round 19
// 910.314 us; speedup vs baseline: 1.4318x; 1.4318x over previous
//
#include <hip/hip_runtime.h>

#define HH 128
#define EAA 16
#define NNODES 100000
#define NEDGES 500000
#define NBATCH (NEDGES / 16)   // 31250 exact
#define NNB    (NNODES / 16)   // 6250 exact
#define CHUNK 512
#define NCHUNK ((NNODES + CHUNK - 1) / CHUNK)  // 196

// global transposed-weight row strides (elements, 16B-multiple)
#define GE1 160   // edge w1t: k in [0,160), real 144, pad zeroed
#define GE2 128
#define GN1 256
#define GN2 128
// edge-kernel LDS weight strides (bank-spread, r7-verified)
#define LW1 168   // 336 B row; 16 A-frag lanes cover all 32 banks 2-way
#define LW2 136   // 272 B row; same property
#define NW 8      // waves per block
#define LROW 136  // merged rows/msg tile stride in u16 (272 B)
#define OTS 36    // node out-tile stride in f32 (144 B, 16B-aligned)

typedef unsigned int u32;
typedef unsigned short u16;
typedef __attribute__((ext_vector_type(8))) short bf16x8;
typedef __attribute__((ext_vector_type(4))) short s16x4;
typedef __attribute__((ext_vector_type(4))) float f32x4;

__device__ __forceinline__ float bf_lo(u32 v){ return __builtin_bit_cast(float, (u32)(v << 16)); }
__device__ __forceinline__ float bf_hi(u32 v){ return __builtin_bit_cast(float, (u32)(v & 0xffff0000u)); }
__device__ __forceinline__ u16 f2bf(float f){
  u32 x = __builtin_bit_cast(u32, f);
  return (u16)((x + 0x7fffu + ((x >> 16) & 1u)) >> 16);
}
__device__ __forceinline__ float sigm(float x){ return 1.0f / (1.0f + __expf(-x)); }
__device__ __forceinline__ uint2 shfl64(uint2 v, int src){
  uint2 r;
  r.x = (u32)__shfl((int)v.x, src, 64);
  r.y = (u32)__shfl((int)v.y, src, 64);
  return r;
}
__device__ __forceinline__ bf16x8 ld8f_bf(const float* p){
  float4 v0 = *(const float4*)(p);
  float4 v1 = *(const float4*)(p + 4);
  uint4 u;
  u.x = ((u32)f2bf(v0.y) << 16) | f2bf(v0.x);
  u.y = ((u32)f2bf(v0.w) << 16) | f2bf(v0.z);
  u.z = ((u32)f2bf(v1.y) << 16) | f2bf(v1.x);
  u.w = ((u32)f2bf(v1.w) << 16) | f2bf(v1.z);
  return __builtin_bit_cast(bf16x8, u);
}

// ===========================================================================
// Weight staging: transpose f32 [K][128] -> bf16 [128][Kpad] (zero pad).
// ===========================================================================
__global__ void stage_weights(
    const float* __restrict__ w1e, const float* __restrict__ w2e, const float* __restrict__ mwe,
    const float* __restrict__ w1n, const float* __restrict__ w2n,
    u16* __restrict__ gw1e, u16* __restrict__ gw2e, u16* __restrict__ gmwe,
    u16* __restrict__ gw1n, u16* __restrict__ gw2n)
{
  const float* src; u16* dst; int K, KP;
  switch (blockIdx.y) {
    case 0: src = w1e; dst = gw1e; K = 144; KP = GE1; break;
    case 1: src = w2e; dst = gw2e; K = 128; KP = GE2; break;
    case 2: src = mwe; dst = gmwe; K = 128; KP = GE2; break;
    case 3: src = w1n; dst = gw1n; K = 256; KP = GN1; break;
    default: src = w2n; dst = gw2n; K = 128; KP = GN2; break;
  }
  int total = 128 * KP;
  for (int i = blockIdx.x * blockDim.x + threadIdx.x; i < total; i += gridDim.x * blockDim.x) {
    int f = i / KP, k = i - f * KP;
    dst[i] = (k < K) ? f2bf(src[(size_t)k * 128 + f]) : (u16)0;
  }
}

// ===========================================================================
// CSR build (both directions fused): count -> scan -> fill.
// fill writes packed per-slot descriptors {src, dstSlot, eid}.
// ===========================================================================
__global__ void count2_k(const int* __restrict__ edges,
                         int* __restrict__ cntA, int* __restrict__ cntB){
  int e = blockIdx.x * blockDim.x + threadIdx.x;
  if (e < NEDGES){
    int2 p = ((const int2*)edges)[e];
    atomicAdd(&cntA[p.y], 1);
    atomicAdd(&cntB[p.x], 1);
  }
}
__global__ void scanA2_k(const int* __restrict__ cntA, const int* __restrict__ cntB,
                         int* __restrict__ offA, int* __restrict__ offB,
                         int* __restrict__ csumA, int* __restrict__ csumB){
  const int* cnt = blockIdx.y ? cntB : cntA;
  int* off  = blockIdx.y ? offB : offA;
  int* csum = blockIdx.y ? csumB : csumA;
  __shared__ int ws[8];
  int i = blockIdx.x * CHUNK + threadIdx.x;
  int v = (i < NNODES) ? cnt[i] : 0;
  int lane = threadIdx.x & 63, w = threadIdx.x >> 6;
  int s = v;
#pragma unroll
  for (int d = 1; d < 64; d <<= 1){ int t = __shfl_up(s, d, 64); if (lane >= d) s += t; }
  if (lane == 63) ws[w] = s;
  __syncthreads();
  if (threadIdx.x == 0){
    int a = 0;
    for (int k = 0; k < 8; k++){ int t = ws[k]; ws[k] = a; a += t; }
    csum[blockIdx.x] = a;
  }
  __syncthreads();
  if (i < NNODES) off[i] = (s - v) + ws[w];
}
__global__ void scanB2_k(int* __restrict__ csumA, int* __restrict__ csumB){
  int lane = threadIdx.x & 63;
  for (int which = 0; which < 2; which++){
    int* c = which ? csumB : csumA;
    int carry = 0;
    for (int base = 0; base < NCHUNK; base += 64){
      int idx = base + lane;
      int v = (idx < NCHUNK) ? c[idx] : 0;
      int s = v;
#pragma unroll
      for (int d = 1; d < 64; d <<= 1){ int t = __shfl_up(s, d, 64); if (lane >= d) s += t; }
      if (idx < NCHUNK) c[idx] = s - v + carry;
      carry += __shfl(s, 63, 64);
    }
  }
}
__global__ void scanC2_k(int* __restrict__ offA, int* __restrict__ offB,
                         int* __restrict__ posA, int* __restrict__ posB,
                         const int* __restrict__ csumA, const int* __restrict__ csumB){
  int* off = blockIdx.y ? offB : offA;
  int* pos = blockIdx.y ? posB : posA;
  const int* csum = blockIdx.y ? csumB : csumA;
  int i = blockIdx.x * blockDim.x + threadIdx.x;
  if (i < NNODES){ int v = off[i] + csum[i / CHUNK]; off[i] = v; pos[i] = v; }
  if (i == 0) off[NNODES] = NEDGES;
}
__global__ void fill2_k(const int* __restrict__ edges,
                        int* __restrict__ posA, int* __restrict__ posB,
                        int4* __restrict__ pairA, int4* __restrict__ pairB){
  int e = blockIdx.x * blockDim.x + threadIdx.x;
  if (e < NEDGES){
    int2 p = ((const int2*)edges)[e];
    int pa = atomicAdd(&posA[p.y], 1);
    int pb = atomicAdd(&posB[p.x], 1);
    pairA[pa] = make_int4(p.y, pb, e, 0);   // phase 2: src = hidden (col 1)
    pairB[pb] = make_int4(p.x, pa, e, 0);   // phase 1: src = clue (col 0)
  }
}

// ===========================================================================
// Edge message kernel — r18 body + WEIGHTS IN LDS (removes the per-batch
// 104-instruction L2 weight stream, the traffic-invariant latency floor).
// Merged rows/msg tile (r12/r14-verified). 149 KB LDS -> 1 block/CU, 8 waves.
// Bank-spread weight strides LW1=168/LW2=136 (r7-verified, 2-way = free).
// ===========================================================================
__global__ __launch_bounds__(512, 2) void edge_msg_w(
    const float* __restrict__ srcN,
    const int4* __restrict__ pair,
    const float* __restrict__ eattr,
    const u16* __restrict__ w1t, const float* __restrict__ b1,
    const u16* __restrict__ w2t, const float* __restrict__ b2,
    const u16* __restrict__ mwt, const float* __restrict__ mb,
    u16* __restrict__ msgs)
{
  __shared__ float b1s[HH], b2s[HH], mbs[HH];                 //  1536 B
  __shared__ alignas(16) u16 w1s[128 * LW1];                  // 43008 B
  __shared__ alignas(16) u16 w2s[128 * LW2];                  // 34816 B
  __shared__ alignas(16) u16 mws[128 * LW2];                  // 34816 B
  __shared__ alignas(16) u16 tile[NW][16 * LROW];             // 34816 B => 148992
  const int tid = threadIdx.x;
  if (tid < HH){ b1s[tid] = b1[tid]; b2s[tid] = b2[tid]; mbs[tid] = mb[tid]; }
  // stage pre-transposed bf16 weights into LDS (strided copy, uint4)
  for (int i = tid; i < 128 * 20; i += 512) {        // w1: 160 u16/row = 20 uint4
    int r = i / 20, c = i - r * 20;
    ((uint4*)(w1s + r * LW1))[c] = ((const uint4*)(w1t + (size_t)r * GE1))[c];
  }
  for (int i = tid; i < 128 * 16; i += 512) {        // w2/mw: 128 u16/row = 16 uint4
    int r = i >> 4, c = i & 15;
    ((uint4*)(w2s + r * LW2))[c] = ((const uint4*)(w2t + (size_t)r * GE2))[c];
    ((uint4*)(mws + r * LW2))[c] = ((const uint4*)(mwt + (size_t)r * GE2))[c];
  }
  __syncthreads();

  const int lane = tid & 63;
  const int wid  = tid >> 6;
  const int q    = lane >> 4;
  const int er   = lane & 15;
  const int ll   = lane & 31;    // row-load lane
  const int half = lane >> 5;    // which of the 2 rows this half-wave loads
  const int gw   = blockIdx.x * NW + wid;
  const int nwv  = gridDim.x * NW;
  const int srcA = 2 * (q & 1) * 16 + er;
  const int srcB = srcA + 16;
  const bool hiT = (q >> 1) != 0;
  u16* mytile = tile[wid];

  for (int b = gw; b < NBATCH; b += nwv) {
    const int e0 = b * 16;
    // single independent descriptor load: {src, dstSlot, eid}
    int4 pr = pair[e0 + er];
    const int s   = pr.x;
    const int dp  = pr.y;
    const int eid = pr.z;

    // ---- coalesced gather: half-wave loads one full 512-B row, bf16 -> LDS
#pragma unroll
    for (int p = 0; p < 8; p++) {
      int j = 2 * p + half;
      int sj = __shfl(s, j, 64);
      float4 v = *(const float4*)(srcN + (size_t)sj * HH + ll * 4);
      uint2 pk;
      pk.x = ((u32)f2bf(v.y) << 16) | f2bf(v.x);
      pk.y = ((u32)f2bf(v.w) << 16) | f2bf(v.z);
      *(s16x4*)(mytile + j * LROW + ll * 4) = __builtin_bit_cast(s16x4, pk);
    }
    asm volatile("" ::: "memory");   // order ds_writes before ds_reads

    // ---- B-frags from LDS + eattr tail
    bf16x8 bs[5];
#pragma unroll
    for (int kt = 0; kt < 4; kt++)
      bs[kt] = *(const bf16x8*)(mytile + er * LROW + kt * 32 + q * 8);
    if (q < 2) bs[4] = ld8f_bf(eattr + (size_t)eid * EAA + q * 8);
    else       bs[4] = (bf16x8){0,0,0,0,0,0,0,0};
    asm volatile("" ::: "memory");   // keep reads before tile reuse

    // ---- stage 1: y^T + SiLU (A-frags from LDS now)
    uint2 pku[8];
#pragma unroll
    for (int t = 0; t < 8; t++) {
      const u16* ap = w1s + (t * 16 + er) * LW1 + q * 8;
      f32x4 acc = {b1s[t*16 + q*4 + 0], b1s[t*16 + q*4 + 1],
                   b1s[t*16 + q*4 + 2], b1s[t*16 + q*4 + 3]};
#pragma unroll
      for (int kt = 0; kt < 5; kt++) {
        bf16x8 af = *(const bf16x8*)(ap + kt * 32);
        acc = __builtin_amdgcn_mfma_f32_16x16x32_bf16(af, bs[kt], acc, 0, 0, 0);
      }
      float v0 = acc[0] * sigm(acc[0]), v1 = acc[1] * sigm(acc[1]);
      float v2 = acc[2] * sigm(acc[2]), v3 = acc[3] * sigm(acc[3]);
      pku[t].x = ((u32)f2bf(v1) << 16) | f2bf(v0);
      pku[t].y = ((u32)f2bf(v3) << 16) | f2bf(v2);
    }

    // ---- D-layout -> B-frag redistribution (in-register)
    bf16x8 yb[4];
#pragma unroll
    for (int kt = 0; kt < 4; kt++) {
      uint2 aLo = shfl64(pku[2*kt],     srcA);
      uint2 aHi = shfl64(pku[2*kt + 1], srcA);
      uint2 bLo = shfl64(pku[2*kt],     srcB);
      uint2 bHi = shfl64(pku[2*kt + 1], srcB);
      uint4 w;
      w.x = hiT ? aHi.x : aLo.x;
      w.y = hiT ? aHi.y : aLo.y;
      w.z = hiT ? bHi.x : bLo.x;
      w.w = hiT ? bHi.y : bLo.y;
      yb[kt] = __builtin_bit_cast(bf16x8, w);
    }

    // ---- stage 2+3: gate & message -> merged tile (WAR-safe: every stored
    //      value data-depends on all bs reads; r12/r14-verified pattern)
#pragma unroll
    for (int t = 0; t < 8; t++) {
      const u16* ap2 = w2s + (t * 16 + er) * LW2 + q * 8;
      const u16* ap3 = mws + (t * 16 + er) * LW2 + q * 8;
      f32x4 g = {b2s[t*16 + q*4 + 0], b2s[t*16 + q*4 + 1],
                 b2s[t*16 + q*4 + 2], b2s[t*16 + q*4 + 3]};
      f32x4 m = {mbs[t*16 + q*4 + 0], mbs[t*16 + q*4 + 1],
                 mbs[t*16 + q*4 + 2], mbs[t*16 + q*4 + 3]};
#pragma unroll
      for (int kt = 0; kt < 4; kt++) {
        bf16x8 a2 = *(const bf16x8*)(ap2 + kt * 32);
        g = __builtin_amdgcn_mfma_f32_16x16x32_bf16(a2, yb[kt], g, 0, 0, 0);
        bf16x8 a3 = *(const bf16x8*)(ap3 + kt * 32);
        m = __builtin_amdgcn_mfma_f32_16x16x32_bf16(a3, bs[kt], m, 0, 0, 0);
      }
      float v0 = m[0] * sigm(g[0]), v1 = m[1] * sigm(g[1]);
      float v2 = m[2] * sigm(g[2]), v3 = m[3] * sigm(g[3]);
      uint2 pk;
      pk.x = ((u32)f2bf(v1) << 16) | f2bf(v0);
      pk.y = ((u32)f2bf(v3) << 16) | f2bf(v2);
      *(s16x4*)(mytile + er * LROW + t * 16 + q * 4) = __builtin_bit_cast(s16x4, pk);
    }
    asm volatile("" ::: "memory");

    // ---- scatter store: quarter-wave per edge, 256 B = 2 full lines
#pragma unroll
    for (int p = 0; p < 4; p++) {
      int e_r = 4 * p + q;
      int dslot = __shfl(dp, e_r, 64);
      bf16x8 v = *(const bf16x8*)(mytile + e_r * LROW + er * 8);
      *(bf16x8*)(msgs + (size_t)dslot * 128 + er * 8) = v;
    }
    asm volatile("" ::: "memory");   // store-reads before next gather writes
  }
}

// ===========================================================================
// Node update — ROUND-16/17/18 VERIFIED FORM: CSR pull-aggregation +
// FULL-LINE out stores via per-wave LDS transpose tile.
// ===========================================================================
__global__ __launch_bounds__(512, 2) void node_csr(
    const float* __restrict__ hin,
    const u16* __restrict__ msgs, const int* __restrict__ off,
    const u16* __restrict__ w1t, const float* __restrict__ b1,
    const u16* __restrict__ w2t, const float* __restrict__ b2,
    const float* __restrict__ lng, const float* __restrict__ lnb,
    float* __restrict__ out)
{
  __shared__ float b1s[HH], b2s[HH], gsv[HH], bsv[HH];
  __shared__ alignas(16) float otile[NW][16 * OTS];   // 18432 B
  const int tid = threadIdx.x;
  if (tid < HH){ b1s[tid] = b1[tid]; b2s[tid] = b2[tid];
                 gsv[tid] = lng[tid]; bsv[tid] = lnb[tid]; }
  __syncthreads();

  const int lane = tid & 63;
  const int wid  = tid >> 6;
  const int q    = lane >> 4;
  const int nr   = lane & 15;
  const int gw   = blockIdx.x * NW + wid;
  const int nwv  = gridDim.x * NW;
  const int srcA = 2 * (q & 1) * 16 + nr;
  const int srcB = srcA + 16;
  const bool hiT = (q >> 1) != 0;
  float* myot = otile[wid];

  for (int nb = gw; nb < NNB; nb += nwv) {
    const int n = nb * 16 + nr;
    const size_t base = (size_t)n * HH;

    // ---- pull-aggregate: contiguous CSR slots of this node
    float av[32];
#pragma unroll
    for (int j = 0; j < 32; j++) av[j] = 0.0f;
    const int beg = off[n], end = off[n + 1];
    for (int i = 0; ; i++) {
      bool act = (beg + i < end);
      if (!__any(act)) break;
      if (act) {
        const u16* mp = msgs + (size_t)(beg + i) * 128 + q * 8;
#pragma unroll
        for (int kt = 0; kt < 4; kt++) {
          uint4 r = *(const uint4*)(mp + kt * 32);
          av[kt*8+0] += bf_lo(r.x); av[kt*8+1] += bf_hi(r.x);
          av[kt*8+2] += bf_lo(r.y); av[kt*8+3] += bf_hi(r.y);
          av[kt*8+4] += bf_lo(r.z); av[kt*8+5] += bf_hi(r.z);
          av[kt*8+6] += bf_lo(r.w); av[kt*8+7] += bf_hi(r.w);
        }
      }
    }

    // ---- B-frags: cat = [hin | agg]
    bf16x8 cb[8];
    const float* hp = hin + base + q * 8;
    cb[0] = ld8f_bf(hp);
    cb[1] = ld8f_bf(hp + 32);
    cb[2] = ld8f_bf(hp + 64);
    cb[3] = ld8f_bf(hp + 96);
#pragma unroll
    for (int kt = 0; kt < 4; kt++) {
      uint4 u;
      u.x = ((u32)f2bf(av[kt*8+1]) << 16) | f2bf(av[kt*8+0]);
      u.y = ((u32)f2bf(av[kt*8+3]) << 16) | f2bf(av[kt*8+2]);
      u.z = ((u32)f2bf(av[kt*8+5]) << 16) | f2bf(av[kt*8+4]);
      u.w = ((u32)f2bf(av[kt*8+7]) << 16) | f2bf(av[kt*8+6]);
      cb[4 + kt] = __builtin_bit_cast(bf16x8, u);
    }

    // ---- stage 1: u^T = relu(w1^T @ cat^T + b1)
    uint2 pku[8];
#pragma unroll
    for (int t = 0; t < 8; t++) {
      const u16* a1p = w1t + (size_t)(t * 16 + nr) * GN1 + q * 8;
      f32x4 acc = {b1s[t*16 + q*4 + 0], b1s[t*16 + q*4 + 1],
                   b1s[t*16 + q*4 + 2], b1s[t*16 + q*4 + 3]};
#pragma unroll
      for (int kt = 0; kt < 8; kt++) {
        bf16x8 af = *(const bf16x8*)(a1p + kt * 32);
        acc = __builtin_amdgcn_mfma_f32_16x16x32_bf16(af, cb[kt], acc, 0, 0, 0);
      }
      float v0 = fmaxf(acc[0], 0.0f), v1 = fmaxf(acc[1], 0.0f);
      float v2 = fmaxf(acc[2], 0.0f), v3 = fmaxf(acc[3], 0.0f);
      pku[t].x = ((u32)f2bf(v1) << 16) | f2bf(v0);
      pku[t].y = ((u32)f2bf(v3) << 16) | f2bf(v2);
    }

    bf16x8 yb[4];
#pragma unroll
    for (int kt = 0; kt < 4; kt++) {
      uint2 aLo = shfl64(pku[2*kt],     srcA);
      uint2 aHi = shfl64(pku[2*kt + 1], srcA);
      uint2 bLo = shfl64(pku[2*kt],     srcB);
      uint2 bHi = shfl64(pku[2*kt + 1], srcB);
      uint4 w;
      w.x = hiT ? aHi.x : aLo.x;
      w.y = hiT ? aHi.y : aLo.y;
      w.z = hiT ? bHi.x : bLo.x;
      w.w = hiT ? bHi.y : bLo.y;
      yb[kt] = __builtin_bit_cast(bf16x8, w);
    }

    // ---- stage 2 + residual + LN
    float xv[8][4];
    float psum = 0.0f;
#pragma unroll
    for (int t = 0; t < 8; t++) {
      const u16* a2p = w2t + (size_t)(t * 16 + nr) * GN2 + q * 8;
      f32x4 uacc = {b2s[t*16 + q*4 + 0], b2s[t*16 + q*4 + 1],
                    b2s[t*16 + q*4 + 2], b2s[t*16 + q*4 + 3]};
#pragma unroll
      for (int kt = 0; kt < 4; kt++) {
        bf16x8 a2 = *(const bf16x8*)(a2p + kt * 32);
        uacc = __builtin_amdgcn_mfma_f32_16x16x32_bf16(a2, yb[kt], uacc, 0, 0, 0);
      }
      float4 hv = *(const float4*)(hin + base + t * 16 + q * 4);
      xv[t][0] = hv.x + uacc[0];
      xv[t][1] = hv.y + uacc[1];
      xv[t][2] = hv.z + uacc[2];
      xv[t][3] = hv.w + uacc[3];
      psum += xv[t][0] + xv[t][1] + xv[t][2] + xv[t][3];
    }
    psum += __shfl_xor(psum, 16, 64);
    psum += __shfl_xor(psum, 32, 64);
    float mu = psum * (1.0f / 128.0f);
    float pvar = 0.0f;
#pragma unroll
    for (int t = 0; t < 8; t++) {
#pragma unroll
      for (int j = 0; j < 4; j++) {
        float dx = xv[t][j] - mu;
        xv[t][j] = dx;
        pvar += dx * dx;
      }
    }
    pvar += __shfl_xor(pvar, 16, 64);
    pvar += __shfl_xor(pvar, 32, 64);
    float inv = rsqrtf(pvar * (1.0f / 128.0f) + 1e-5f);
#pragma unroll
    for (int t = 0; t < 8; t++) {
      int F = t * 16 + q * 4;
      xv[t][0] = xv[t][0] * inv * gsv[F + 0] + bsv[F + 0];
      xv[t][1] = xv[t][1] * inv * gsv[F + 1] + bsv[F + 1];
      xv[t][2] = xv[t][2] * inv * gsv[F + 2] + bsv[F + 2];
      xv[t][3] = xv[t][3] * inv * gsv[F + 3] + bsv[F + 3];
    }

    // ---- full-line out stores via LDS transpose tile.
#pragma unroll
    for (int tp = 0; tp < 4; tp++) {
      asm volatile("" ::: "memory");   // previous tp's reads before overwrite
#pragma unroll
      for (int dt = 0; dt < 2; dt++) {
        int t = 2 * tp + dt;
        float4 v; v.x = xv[t][0]; v.y = xv[t][1]; v.z = xv[t][2]; v.w = xv[t][3];
        *(float4*)(myot + nr * OTS + dt * 16 + q * 4) = v;
      }
      asm volatile("" ::: "memory");
#pragma unroll
      for (int hf = 0; hf < 2; hf++) {
        int n8 = hf * 8 + (lane >> 3);
        int f  = (lane & 7) * 4;
        float4 v = *(const float4*)(myot + n8 * OTS + f);
        *(float4*)(out + (size_t)(nb * 16 + n8) * HH + tp * 32 + f) = v;
      }
    }
  }
}

// ===========================================================================
extern "C" void kernel_launch(void* const* d_in, const int* in_sizes, int n_in,
                              void* d_out, int out_size, void* d_ws, size_t ws_size,
                              hipStream_t stream) {
  const float* h_hidden = (const float*)d_in[0];
  const float* h_clue   = (const float*)d_in[1];
  const int*   edges    = (const int*)d_in[2];
  const float* eattr    = (const float*)d_in[3];
  const float* c2h_g_w1 = (const float*)d_in[4];  const float* c2h_g_b1 = (const float*)d_in[5];
  const float* c2h_g_w2 = (const float*)d_in[6];  const float* c2h_g_b2 = (const float*)d_in[7];
  const float* c2h_m_w  = (const float*)d_in[8];  const float* c2h_m_b  = (const float*)d_in[9];
  const float* h_u_w1   = (const float*)d_in[10]; const float* h_u_b1   = (const float*)d_in[11];
  const float* h_u_w2   = (const float*)d_in[12]; const float* h_u_b2   = (const float*)d_in[13];
  const float* h_ln_g   = (const float*)d_in[14]; const float* h_ln_b   = (const float*)d_in[15];
  const float* h2c_g_w1 = (const float*)d_in[16]; const float* h2c_g_b1 = (const float*)d_in[17];
  const float* h2c_g_w2 = (const float*)d_in[18]; const float* h2c_g_b2 = (const float*)d_in[19];
  const float* h2c_m_w  = (const float*)d_in[20]; const float* h2c_m_b  = (const float*)d_in[21];
  const float* c_u_w1   = (const float*)d_in[22]; const float* c_u_b1   = (const float*)d_in[23];
  const float* c_u_w2   = (const float*)d_in[24]; const float* c_u_b2   = (const float*)d_in[25];
  const float* c_ln_g   = (const float*)d_in[26]; const float* c_ln_b   = (const float*)d_in[27];

  float* out_hidden = (float*)d_out;
  float* out_clue   = (float*)d_out + (size_t)NNODES * HH;

  // ---- workspace carve-up
  char* W = (char*)d_ws;
  size_t woff = 0;
  auto take = [&](size_t nbytes) -> char* {
    char* p = W + woff;
    woff += (nbytes + 255) & ~(size_t)255;
    return p;
  };
  u16*  msgs  = (u16*)take((size_t)NEDGES * HH * 2);       // 128 MB
  int*  cntA  = (int*)take((size_t)NNODES * 2 * 4);        // contiguous pair
  int*  cntB  = cntA + NNODES;
  int*  offA  = (int*)take((size_t)(NNODES + 1) * 4);
  int*  offB  = (int*)take((size_t)(NNODES + 1) * 4);
  int*  posA  = (int*)take((size_t)NNODES * 4);
  int*  posB  = (int*)take((size_t)NNODES * 4);
  int4* pairA = (int4*)take((size_t)NEDGES * 16);          // 8 MB
  int4* pairB = (int4*)take((size_t)NEDGES * 16);          // 8 MB
  int*  csumA = (int*)take((size_t)NCHUNK * 4);
  int*  csumB = (int*)take((size_t)NCHUNK * 4);
  u16* gw1eA  = (u16*)take(128 * GE1 * 2);
  u16* gw2eA  = (u16*)take(128 * GE2 * 2);
  u16* gmweA  = (u16*)take(128 * GE2 * 2);
  u16* gw1nA  = (u16*)take(128 * GN1 * 2);
  u16* gw2nA  = (u16*)take(128 * GN2 * 2);
  u16* gw1eB  = (u16*)take(128 * GE1 * 2);
  u16* gw2eB  = (u16*)take(128 * GE2 * 2);
  u16* gmweB  = (u16*)take(128 * GE2 * 2);
  u16* gw1nB  = (u16*)take(128 * GN1 * 2);
  u16* gw2nB  = (u16*)take(128 * GN2 * 2);

  const int EB = (NEDGES + 255) / 256;
  const int NB = (NNODES + 255) / 256;

  // stage all weights (bf16, transposed)
  stage_weights<<<dim3(16, 5), 256, 0, stream>>>(
      c2h_g_w1, c2h_g_w2, c2h_m_w, h_u_w1, h_u_w2,
      gw1eA, gw2eA, gmweA, gw1nA, gw2nA);
  stage_weights<<<dim3(16, 5), 256, 0, stream>>>(
      h2c_g_w1, h2c_g_w2, h2c_m_w, c_u_w1, c_u_w2,
      gw1eB, gw2eB, gmweB, gw1nB, gw2nB);

  // CSR build (both directions, fused; fill writes packed descriptors)
  hipMemsetAsync(cntA, 0, (size_t)NNODES * 2 * 4, stream);
  count2_k<<<EB, 256, 0, stream>>>(edges, cntA, cntB);
  scanA2_k<<<dim3(NCHUNK, 2), CHUNK, 0, stream>>>(cntA, cntB, offA, offB, csumA, csumB);
  scanB2_k<<<1, 64, 0, stream>>>(csumA, csumB);
  scanC2_k<<<dim3(NB, 2), 256, 0, stream>>>(offA, offB, posA, posB, csumA, csumB);
  fill2_k<<<EB, 256, 0, stream>>>(edges, posA, posB, pairA, pairB);

  // Phase 1: clue -> hidden. pairB is src(clue)-sorted; dstSlot -> CSR-A.
  edge_msg_w<<<256, 512, 0, stream>>>(h_clue, pairB, eattr,
      gw1eA, c2h_g_b1, gw2eA, c2h_g_b2, gmweA, c2h_m_b, msgs);
  node_csr<<<512, 512, 0, stream>>>(h_hidden, msgs, offA,
      gw1nA, h_u_b1, gw2nA, h_u_b2, h_ln_g, h_ln_b, out_hidden);

  // Phase 2: hidden_new -> clue. pairA is src(hidden)-sorted; dstSlot -> CSR-B.
  edge_msg_w<<<256, 512, 0, stream>>>(out_hidden, pairA, eattr,
      gw1eB, h2c_g_b1, gw2eB, h2c_g_b2, gmweB, h2c_m_b, msgs);
  node_csr<<<512, 512, 0, stream>>>(h_clue, msgs, offB,
      gw1nB, c_u_b1, gw2nB, c_u_b2, c_ln_g, c_ln_b, out_clue);
}

// Round 20
// 550.175 us; speedup vs baseline: 2.3690x; 1.6546x over previous
//
#include <hip/hip_runtime.h>

#define HH 128
#define EAA 16
#define NNODES 100000
#define NEDGES 500000
#define NBATCH (NEDGES / 16)   // 31250 exact
#define NNB    (NNODES / 16)   // 6250 exact
#define CHUNK 512
#define NCHUNK ((NNODES + CHUNK - 1) / CHUNK)  // 196

// global transposed-weight row strides (elements, 16B-multiple)
#define GE1 160   // edge w1t: k in [0,160), real 144, pad zeroed
#define GE2 128
#define GN1 256
#define GN2 128
// edge-kernel LDS weight strides (bank-spread, r7/r19-verified)
#define LW1 168
#define LW2 136
// node-kernel LDS weight strides
#define LN1 264   // 528 B row (33x16B); 2-way bank pattern on A-frag reads
#define LN2 136
#define NW 8      // waves per block
#define LROW 136  // merged rows/msg tile stride in u16 (272 B)
#define OTS 36    // node out-tile stride in f32 (144 B, 16B-aligned)

typedef unsigned int u32;
typedef unsigned short u16;
typedef __attribute__((ext_vector_type(8))) short bf16x8;
typedef __attribute__((ext_vector_type(4))) short s16x4;
typedef __attribute__((ext_vector_type(4))) float f32x4;

__device__ __forceinline__ float bf_lo(u32 v){ return __builtin_bit_cast(float, (u32)(v << 16)); }
__device__ __forceinline__ float bf_hi(u32 v){ return __builtin_bit_cast(float, (u32)(v & 0xffff0000u)); }
__device__ __forceinline__ u16 f2bf(float f){
  u32 x = __builtin_bit_cast(u32, f);
  return (u16)((x + 0x7fffu + ((x >> 16) & 1u)) >> 16);
}
__device__ __forceinline__ float sigm(float x){ return 1.0f / (1.0f + __expf(-x)); }
__device__ __forceinline__ uint2 shfl64(uint2 v, int src){
  uint2 r;
  r.x = (u32)__shfl((int)v.x, src, 64);
  r.y = (u32)__shfl((int)v.y, src, 64);
  return r;
}
__device__ __forceinline__ bf16x8 ld8f_bf(const float* p){
  float4 v0 = *(const float4*)(p);
  float4 v1 = *(const float4*)(p + 4);
  uint4 u;
  u.x = ((u32)f2bf(v0.y) << 16) | f2bf(v0.x);
  u.y = ((u32)f2bf(v0.w) << 16) | f2bf(v0.z);
  u.z = ((u32)f2bf(v1.y) << 16) | f2bf(v1.x);
  u.w = ((u32)f2bf(v1.w) << 16) | f2bf(v1.z);
  return __builtin_bit_cast(bf16x8, u);
}

// ===========================================================================
// Weight staging: transpose f32 [K][128] -> bf16 [128][Kpad] (zero pad).
// ===========================================================================
__global__ void stage_weights(
    const float* __restrict__ w1e, const float* __restrict__ w2e, const float* __restrict__ mwe,
    const float* __restrict__ w1n, const float* __restrict__ w2n,
    u16* __restrict__ gw1e, u16* __restrict__ gw2e, u16* __restrict__ gmwe,
    u16* __restrict__ gw1n, u16* __restrict__ gw2n)
{
  const float* src; u16* dst; int K, KP;
  switch (blockIdx.y) {
    case 0: src = w1e; dst = gw1e; K = 144; KP = GE1; break;
    case 1: src = w2e; dst = gw2e; K = 128; KP = GE2; break;
    case 2: src = mwe; dst = gmwe; K = 128; KP = GE2; break;
    case 3: src = w1n; dst = gw1n; K = 256; KP = GN1; break;
    default: src = w2n; dst = gw2n; K = 128; KP = GN2; break;
  }
  int total = 128 * KP;
  for (int i = blockIdx.x * blockDim.x + threadIdx.x; i < total; i += gridDim.x * blockDim.x) {
    int f = i / KP, k = i - f * KP;
    dst[i] = (k < K) ? f2bf(src[(size_t)k * 128 + f]) : (u16)0;
  }
}

// ===========================================================================
// CSR build (both directions fused): count -> scan -> fill.
// fill writes packed per-slot descriptors {src, dstSlot, eid}.
// ===========================================================================
__global__ void count2_k(const int* __restrict__ edges,
                         int* __restrict__ cntA, int* __restrict__ cntB){
  int e = blockIdx.x * blockDim.x + threadIdx.x;
  if (e < NEDGES){
    int2 p = ((const int2*)edges)[e];
    atomicAdd(&cntA[p.y], 1);
    atomicAdd(&cntB[p.x], 1);
  }
}
__global__ void scanA2_k(const int* __restrict__ cntA, const int* __restrict__ cntB,
                         int* __restrict__ offA, int* __restrict__ offB,
                         int* __restrict__ csumA, int* __restrict__ csumB){
  const int* cnt = blockIdx.y ? cntB : cntA;
  int* off  = blockIdx.y ? offB : offA;
  int* csum = blockIdx.y ? csumB : csumA;
  __shared__ int ws[8];
  int i = blockIdx.x * CHUNK + threadIdx.x;
  int v = (i < NNODES) ? cnt[i] : 0;
  int lane = threadIdx.x & 63, w = threadIdx.x >> 6;
  int s = v;
#pragma unroll
  for (int d = 1; d < 64; d <<= 1){ int t = __shfl_up(s, d, 64); if (lane >= d) s += t; }
  if (lane == 63) ws[w] = s;
  __syncthreads();
  if (threadIdx.x == 0){
    int a = 0;
    for (int k = 0; k < 8; k++){ int t = ws[k]; ws[k] = a; a += t; }
    csum[blockIdx.x] = a;
  }
  __syncthreads();
  if (i < NNODES) off[i] = (s - v) + ws[w];
}
__global__ void scanB2_k(int* __restrict__ csumA, int* __restrict__ csumB){
  int lane = threadIdx.x & 63;
  for (int which = 0; which < 2; which++){
    int* c = which ? csumB : csumA;
    int carry = 0;
    for (int base = 0; base < NCHUNK; base += 64){
      int idx = base + lane;
      int v = (idx < NCHUNK) ? c[idx] : 0;
      int s = v;
#pragma unroll
      for (int d = 1; d < 64; d <<= 1){ int t = __shfl_up(s, d, 64); if (lane >= d) s += t; }
      if (idx < NCHUNK) c[idx] = s - v + carry;
      carry += __shfl(s, 63, 64);
    }
  }
}
__global__ void scanC2_k(int* __restrict__ offA, int* __restrict__ offB,
                         int* __restrict__ posA, int* __restrict__ posB,
                         const int* __restrict__ csumA, const int* __restrict__ csumB){
  int* off = blockIdx.y ? offB : offA;
  int* pos = blockIdx.y ? posB : posA;
  const int* csum = blockIdx.y ? csumB : csumA;
  int i = blockIdx.x * blockDim.x + threadIdx.x;
  if (i < NNODES){ int v = off[i] + csum[i / CHUNK]; off[i] = v; pos[i] = v; }
  if (i == 0) off[NNODES] = NEDGES;
}
__global__ void fill2_k(const int* __restrict__ edges,
                        int* __restrict__ posA, int* __restrict__ posB,
                        int4* __restrict__ pairA, int4* __restrict__ pairB){
  int e = blockIdx.x * blockDim.x + threadIdx.x;
  if (e < NEDGES){
    int2 p = ((const int2*)edges)[e];
    int pa = atomicAdd(&posA[p.y], 1);
    int pb = atomicAdd(&posB[p.x], 1);
    pairA[pa] = make_int4(p.y, pb, e, 0);   // phase 2: src = hidden (col 1)
    pairB[pb] = make_int4(p.x, pa, e, 0);   // phase 1: src = clue (col 0)
  }
}

// ===========================================================================
// Edge message kernel — ROUND-19 VERIFIED FORM (weights in LDS, merged tile,
// descriptor loads, SRC-sorted, scatter to dst-CSR slot). 149 KB LDS.
// ===========================================================================
__global__ __launch_bounds__(512, 2) void edge_msg_w(
    const float* __restrict__ srcN,
    const int4* __restrict__ pair,
    const float* __restrict__ eattr,
    const u16* __restrict__ w1t, const float* __restrict__ b1,
    const u16* __restrict__ w2t, const float* __restrict__ b2,
    const u16* __restrict__ mwt, const float* __restrict__ mb,
    u16* __restrict__ msgs)
{
  __shared__ float b1s[HH], b2s[HH], mbs[HH];                 //  1536 B
  __shared__ alignas(16) u16 w1s[128 * LW1];                  // 43008 B
  __shared__ alignas(16) u16 w2s[128 * LW2];                  // 34816 B
  __shared__ alignas(16) u16 mws[128 * LW2];                  // 34816 B
  __shared__ alignas(16) u16 tile[NW][16 * LROW];             // 34816 B => 148992
  const int tid = threadIdx.x;
  if (tid < HH){ b1s[tid] = b1[tid]; b2s[tid] = b2[tid]; mbs[tid] = mb[tid]; }
  for (int i = tid; i < 128 * 20; i += 512) {        // w1: 160 u16/row = 20 uint4
    int r = i / 20, c = i - r * 20;
    ((uint4*)(w1s + r * LW1))[c] = ((const uint4*)(w1t + (size_t)r * GE1))[c];
  }
  for (int i = tid; i < 128 * 16; i += 512) {        // w2/mw: 16 uint4/row
    int r = i >> 4, c = i & 15;
    ((uint4*)(w2s + r * LW2))[c] = ((const uint4*)(w2t + (size_t)r * GE2))[c];
    ((uint4*)(mws + r * LW2))[c] = ((const uint4*)(mwt + (size_t)r * GE2))[c];
  }
  __syncthreads();

  const int lane = tid & 63;
  const int wid  = tid >> 6;
  const int q    = lane >> 4;
  const int er   = lane & 15;
  const int ll   = lane & 31;
  const int half = lane >> 5;
  const int gw   = blockIdx.x * NW + wid;
  const int nwv  = gridDim.x * NW;
  const int srcA = 2 * (q & 1) * 16 + er;
  const int srcB = srcA + 16;
  const bool hiT = (q >> 1) != 0;
  u16* mytile = tile[wid];

  for (int b = gw; b < NBATCH; b += nwv) {
    const int e0 = b * 16;
    int4 pr = pair[e0 + er];
    const int s   = pr.x;
    const int dp  = pr.y;
    const int eid = pr.z;

    // ---- coalesced gather: half-wave loads one full 512-B row, bf16 -> LDS
#pragma unroll
    for (int p = 0; p < 8; p++) {
      int j = 2 * p + half;
      int sj = __shfl(s, j, 64);
      float4 v = *(const float4*)(srcN + (size_t)sj * HH + ll * 4);
      uint2 pk;
      pk.x = ((u32)f2bf(v.y) << 16) | f2bf(v.x);
      pk.y = ((u32)f2bf(v.w) << 16) | f2bf(v.z);
      *(s16x4*)(mytile + j * LROW + ll * 4) = __builtin_bit_cast(s16x4, pk);
    }
    asm volatile("" ::: "memory");

    // ---- B-frags from LDS + eattr tail
    bf16x8 bs[5];
#pragma unroll
    for (int kt = 0; kt < 4; kt++)
      bs[kt] = *(const bf16x8*)(mytile + er * LROW + kt * 32 + q * 8);
    if (q < 2) bs[4] = ld8f_bf(eattr + (size_t)eid * EAA + q * 8);
    else       bs[4] = (bf16x8){0,0,0,0,0,0,0,0};
    asm volatile("" ::: "memory");

    // ---- stage 1: y^T + SiLU (A-frags from LDS)
    uint2 pku[8];
#pragma unroll
    for (int t = 0; t < 8; t++) {
      const u16* ap = w1s + (t * 16 + er) * LW1 + q * 8;
      f32x4 acc = {b1s[t*16 + q*4 + 0], b1s[t*16 + q*4 + 1],
                   b1s[t*16 + q*4 + 2], b1s[t*16 + q*4 + 3]};
#pragma unroll
      for (int kt = 0; kt < 5; kt++) {
        bf16x8 af = *(const bf16x8*)(ap + kt * 32);
        acc = __builtin_amdgcn_mfma_f32_16x16x32_bf16(af, bs[kt], acc, 0, 0, 0);
      }
      float v0 = acc[0] * sigm(acc[0]), v1 = acc[1] * sigm(acc[1]);
      float v2 = acc[2] * sigm(acc[2]), v3 = acc[3] * sigm(acc[3]);
      pku[t].x = ((u32)f2bf(v1) << 16) | f2bf(v0);
      pku[t].y = ((u32)f2bf(v3) << 16) | f2bf(v2);
    }

    // ---- D-layout -> B-frag redistribution (in-register)
    bf16x8 yb[4];
#pragma unroll
    for (int kt = 0; kt < 4; kt++) {
      uint2 aLo = shfl64(pku[2*kt],     srcA);
      uint2 aHi = shfl64(pku[2*kt + 1], srcA);
      uint2 bLo = shfl64(pku[2*kt],     srcB);
      uint2 bHi = shfl64(pku[2*kt + 1], srcB);
      uint4 w;
      w.x = hiT ? aHi.x : aLo.x;
      w.y = hiT ? aHi.y : aLo.y;
      w.z = hiT ? bHi.x : bLo.x;
      w.w = hiT ? bHi.y : bLo.y;
      yb[kt] = __builtin_bit_cast(bf16x8, w);
    }

    // ---- stage 2+3: gate & message -> merged tile (WAR-safe)
#pragma unroll
    for (int t = 0; t < 8; t++) {
      const u16* ap2 = w2s + (t * 16 + er) * LW2 + q * 8;
      const u16* ap3 = mws + (t * 16 + er) * LW2 + q * 8;
      f32x4 g = {b2s[t*16 + q*4 + 0], b2s[t*16 + q*4 + 1],
                 b2s[t*16 + q*4 + 2], b2s[t*16 + q*4 + 3]};
      f32x4 m = {mbs[t*16 + q*4 + 0], mbs[t*16 + q*4 + 1],
                 mbs[t*16 + q*4 + 2], mbs[t*16 + q*4 + 3]};
#pragma unroll
      for (int kt = 0; kt < 4; kt++) {
        bf16x8 a2 = *(const bf16x8*)(ap2 + kt * 32);
        g = __builtin_amdgcn_mfma_f32_16x16x32_bf16(a2, yb[kt], g, 0, 0, 0);
        bf16x8 a3 = *(const bf16x8*)(ap3 + kt * 32);
        m = __builtin_amdgcn_mfma_f32_16x16x32_bf16(a3, bs[kt], m, 0, 0, 0);
      }
      float v0 = m[0] * sigm(g[0]), v1 = m[1] * sigm(g[1]);
      float v2 = m[2] * sigm(g[2]), v3 = m[3] * sigm(g[3]);
      uint2 pk;
      pk.x = ((u32)f2bf(v1) << 16) | f2bf(v0);
      pk.y = ((u32)f2bf(v3) << 16) | f2bf(v2);
      *(s16x4*)(mytile + er * LROW + t * 16 + q * 4) = __builtin_bit_cast(s16x4, pk);
    }
    asm volatile("" ::: "memory");

    // ---- scatter store: quarter-wave per edge, 256 B = 2 full lines
#pragma unroll
    for (int p = 0; p < 4; p++) {
      int e_r = 4 * p + q;
      int dslot = __shfl(dp, e_r, 64);
      bf16x8 v = *(const bf16x8*)(mytile + e_r * LROW + er * 8);
      *(bf16x8*)(msgs + (size_t)dslot * 128 + er * 8) = v;
    }
    asm volatile("" ::: "memory");
  }
}

// ===========================================================================
// Node update — r19 body + WEIGHTS IN LDS (removes per-batch 96-instruction
// L2 weight stream, same fix that won on edge). 123 KB LDS -> 1 block/CU.
// ===========================================================================
__global__ __launch_bounds__(512, 2) void node_csr(
    const float* __restrict__ hin,
    const u16* __restrict__ msgs, const int* __restrict__ off,
    const u16* __restrict__ w1t, const float* __restrict__ b1,
    const u16* __restrict__ w2t, const float* __restrict__ b2,
    const float* __restrict__ lng, const float* __restrict__ lnb,
    float* __restrict__ out)
{
  __shared__ float b1s[HH], b2s[HH], gsv[HH], bsv[HH];        //  2048 B
  __shared__ alignas(16) u16 w1s[128 * LN1];                  // 67584 B
  __shared__ alignas(16) u16 w2s[128 * LN2];                  // 34816 B
  __shared__ alignas(16) float otile[NW][16 * OTS];           // 18432 B => 122880
  const int tid = threadIdx.x;
  if (tid < HH){ b1s[tid] = b1[tid]; b2s[tid] = b2[tid];
                 gsv[tid] = lng[tid]; bsv[tid] = lnb[tid]; }
  for (int i = tid; i < 128 * 32; i += 512) {        // w1: 256 u16/row = 32 uint4
    int r = i >> 5, c = i & 31;
    ((uint4*)(w1s + r * LN1))[c] = ((const uint4*)(w1t + (size_t)r * GN1))[c];
  }
  for (int i = tid; i < 128 * 16; i += 512) {        // w2: 16 uint4/row
    int r = i >> 4, c = i & 15;
    ((uint4*)(w2s + r * LN2))[c] = ((const uint4*)(w2t + (size_t)r * GN2))[c];
  }
  __syncthreads();

  const int lane = tid & 63;
  const int wid  = tid >> 6;
  const int q    = lane >> 4;
  const int nr   = lane & 15;
  const int gw   = blockIdx.x * NW + wid;
  const int nwv  = gridDim.x * NW;
  const int srcA = 2 * (q & 1) * 16 + nr;
  const int srcB = srcA + 16;
  const bool hiT = (q >> 1) != 0;
  float* myot = otile[wid];

  for (int nb = gw; nb < NNB; nb += nwv) {
    const int n = nb * 16 + nr;
    const size_t base = (size_t)n * HH;

    // ---- pull-aggregate: contiguous CSR slots of this node
    float av[32];
#pragma unroll
    for (int j = 0; j < 32; j++) av[j] = 0.0f;
    const int beg = off[n], end = off[n + 1];
    for (int i = 0; ; i++) {
      bool act = (beg + i < end);
      if (!__any(act)) break;
      if (act) {
        const u16* mp = msgs + (size_t)(beg + i) * 128 + q * 8;
#pragma unroll
        for (int kt = 0; kt < 4; kt++) {
          uint4 r = *(const uint4*)(mp + kt * 32);
          av[kt*8+0] += bf_lo(r.x); av[kt*8+1] += bf_hi(r.x);
          av[kt*8+2] += bf_lo(r.y); av[kt*8+3] += bf_hi(r.y);
          av[kt*8+4] += bf_lo(r.z); av[kt*8+5] += bf_hi(r.z);
          av[kt*8+6] += bf_lo(r.w); av[kt*8+7] += bf_hi(r.w);
        }
      }
    }

    // ---- B-frags: cat = [hin | agg]
    bf16x8 cb[8];
    const float* hp = hin + base + q * 8;
    cb[0] = ld8f_bf(hp);
    cb[1] = ld8f_bf(hp + 32);
    cb[2] = ld8f_bf(hp + 64);
    cb[3] = ld8f_bf(hp + 96);
#pragma unroll
    for (int kt = 0; kt < 4; kt++) {
      uint4 u;
      u.x = ((u32)f2bf(av[kt*8+1]) << 16) | f2bf(av[kt*8+0]);
      u.y = ((u32)f2bf(av[kt*8+3]) << 16) | f2bf(av[kt*8+2]);
      u.z = ((u32)f2bf(av[kt*8+5]) << 16) | f2bf(av[kt*8+4]);
      u.w = ((u32)f2bf(av[kt*8+7]) << 16) | f2bf(av[kt*8+6]);
      cb[4 + kt] = __builtin_bit_cast(bf16x8, u);
    }

    // ---- stage 1: u^T = relu(w1^T @ cat^T + b1)  (A-frags from LDS)
    uint2 pku[8];
#pragma unroll
    for (int t = 0; t < 8; t++) {
      const u16* a1p = w1s + (t * 16 + nr) * LN1 + q * 8;
      f32x4 acc = {b1s[t*16 + q*4 + 0], b1s[t*16 + q*4 + 1],
                   b1s[t*16 + q*4 + 2], b1s[t*16 + q*4 + 3]};
#pragma unroll
      for (int kt = 0; kt < 8; kt++) {
        bf16x8 af = *(const bf16x8*)(a1p + kt * 32);
        acc = __builtin_amdgcn_mfma_f32_16x16x32_bf16(af, cb[kt], acc, 0, 0, 0);
      }
      float v0 = fmaxf(acc[0], 0.0f), v1 = fmaxf(acc[1], 0.0f);
      float v2 = fmaxf(acc[2], 0.0f), v3 = fmaxf(acc[3], 0.0f);
      pku[t].x = ((u32)f2bf(v1) << 16) | f2bf(v0);
      pku[t].y = ((u32)f2bf(v3) << 16) | f2bf(v2);
    }

    bf16x8 yb[4];
#pragma unroll
    for (int kt = 0; kt < 4; kt++) {
      uint2 aLo = shfl64(pku[2*kt],     srcA);
      uint2 aHi = shfl64(pku[2*kt + 1], srcA);
      uint2 bLo = shfl64(pku[2*kt],     srcB);
      uint2 bHi = shfl64(pku[2*kt + 1], srcB);
      uint4 w;
      w.x = hiT ? aHi.x : aLo.x;
      w.y = hiT ? aHi.y : aLo.y;
      w.z = hiT ? bHi.x : bLo.x;
      w.w = hiT ? bHi.y : bLo.y;
      yb[kt] = __builtin_bit_cast(bf16x8, w);
    }

    // ---- stage 2 + residual + LN  (A-frags from LDS)
    float xv[8][4];
    float psum = 0.0f;
#pragma unroll
    for (int t = 0; t < 8; t++) {
      const u16* a2p = w2s + (t * 16 + nr) * LN2 + q * 8;
      f32x4 uacc = {b2s[t*16 + q*4 + 0], b2s[t*16 + q*4 + 1],
                    b2s[t*16 + q*4 + 2], b2s[t*16 + q*4 + 3]};
#pragma unroll
      for (int kt = 0; kt < 4; kt++) {
        bf16x8 a2 = *(const bf16x8*)(a2p + kt * 32);
        uacc = __builtin_amdgcn_mfma_f32_16x16x32_bf16(a2, yb[kt], uacc, 0, 0, 0);
      }
      float4 hv = *(const float4*)(hin + base + t * 16 + q * 4);
      xv[t][0] = hv.x + uacc[0];
      xv[t][1] = hv.y + uacc[1];
      xv[t][2] = hv.z + uacc[2];
      xv[t][3] = hv.w + uacc[3];
      psum += xv[t][0] + xv[t][1] + xv[t][2] + xv[t][3];
    }
    psum += __shfl_xor(psum, 16, 64);
    psum += __shfl_xor(psum, 32, 64);
    float mu = psum * (1.0f / 128.0f);
    float pvar = 0.0f;
#pragma unroll
    for (int t = 0; t < 8; t++) {
#pragma unroll
      for (int j = 0; j < 4; j++) {
        float dx = xv[t][j] - mu;
        xv[t][j] = dx;
        pvar += dx * dx;
      }
    }
    pvar += __shfl_xor(pvar, 16, 64);
    pvar += __shfl_xor(pvar, 32, 64);
    float inv = rsqrtf(pvar * (1.0f / 128.0f) + 1e-5f);
#pragma unroll
    for (int t = 0; t < 8; t++) {
      int F = t * 16 + q * 4;
      xv[t][0] = xv[t][0] * inv * gsv[F + 0] + bsv[F + 0];
      xv[t][1] = xv[t][1] * inv * gsv[F + 1] + bsv[F + 1];
      xv[t][2] = xv[t][2] * inv * gsv[F + 2] + bsv[F + 2];
      xv[t][3] = xv[t][3] * inv * gsv[F + 3] + bsv[F + 3];
    }

    // ---- full-line out stores via LDS transpose tile.
#pragma unroll
    for (int tp = 0; tp < 4; tp++) {
      asm volatile("" ::: "memory");
#pragma unroll
      for (int dt = 0; dt < 2; dt++) {
        int t = 2 * tp + dt;
        float4 v; v.x = xv[t][0]; v.y = xv[t][1]; v.z = xv[t][2]; v.w = xv[t][3];
        *(float4*)(myot + nr * OTS + dt * 16 + q * 4) = v;
      }
      asm volatile("" ::: "memory");
#pragma unroll
      for (int hf = 0; hf < 2; hf++) {
        int n8 = hf * 8 + (lane >> 3);
        int f  = (lane & 7) * 4;
        float4 v = *(const float4*)(myot + n8 * OTS + f);
        *(float4*)(out + (size_t)(nb * 16 + n8) * HH + tp * 32 + f) = v;
      }
    }
  }
}

// ===========================================================================
extern "C" void kernel_launch(void* const* d_in, const int* in_sizes, int n_in,
                              void* d_out, int out_size, void* d_ws, size_t ws_size,
                              hipStream_t stream) {
  const float* h_hidden = (const float*)d_in[0];
  const float* h_clue   = (const float*)d_in[1];
  const int*   edges    = (const int*)d_in[2];
  const float* eattr    = (const float*)d_in[3];
  const float* c2h_g_w1 = (const float*)d_in[4];  const float* c2h_g_b1 = (const float*)d_in[5];
  const float* c2h_g_w2 = (const float*)d_in[6];  const float* c2h_g_b2 = (const float*)d_in[7];
  const float* c2h_m_w  = (const float*)d_in[8];  const float* c2h_m_b  = (const float*)d_in[9];
  const float* h_u_w1   = (const float*)d_in[10]; const float* h_u_b1   = (const float*)d_in[11];
  const float* h_u_w2   = (const float*)d_in[12]; const float* h_u_b2   = (const float*)d_in[13];
  const float* h_ln_g   = (const float*)d_in[14]; const float* h_ln_b   = (const float*)d_in[15];
  const float* h2c_g_w1 = (const float*)d_in[16]; const float* h2c_g_b1 = (const float*)d_in[17];
  const float* h2c_g_w2 = (const float*)d_in[18]; const float* h2c_g_b2 = (const float*)d_in[19];
  const float* h2c_m_w  = (const float*)d_in[20]; const float* h2c_m_b  = (const float*)d_in[21];
  const float* c_u_w1   = (const float*)d_in[22]; const float* c_u_b1   = (const float*)d_in[23];
  const float* c_u_w2   = (const float*)d_in[24]; const float* c_u_b2   = (const float*)d_in[25];
  const float* c_ln_g   = (const float*)d_in[26]; const float* c_ln_b   = (const float*)d_in[27];

  float* out_hidden = (float*)d_out;
  float* out_clue   = (float*)d_out + (size_t)NNODES * HH;

  // ---- workspace carve-up
  char* W = (char*)d_ws;
  size_t woff = 0;
  auto take = [&](size_t nbytes) -> char* {
    char* p = W + woff;
    woff += (nbytes + 255) & ~(size_t)255;
    return p;
  };
  u16*  msgs  = (u16*)take((size_t)NEDGES * HH * 2);       // 128 MB
  int*  cntA  = (int*)take((size_t)NNODES * 2 * 4);        // contiguous pair
  int*  cntB  = cntA + NNODES;
  int*  offA  = (int*)take((size_t)(NNODES + 1) * 4);
  int*  offB  = (int*)take((size_t)(NNODES + 1) * 4);
  int*  posA  = (int*)take((size_t)NNODES * 4);
  int*  posB  = (int*)take((size_t)NNODES * 4);
  int4* pairA = (int4*)take((size_t)NEDGES * 16);          // 8 MB
  int4* pairB = (int4*)take((size_t)NEDGES * 16);          // 8 MB
  int*  csumA = (int*)take((size_t)NCHUNK * 4);
  int*  csumB = (int*)take((size_t)NCHUNK * 4);
  u16* gw1eA  = (u16*)take(128 * GE1 * 2);
  u16* gw2eA  = (u16*)take(128 * GE2 * 2);
  u16* gmweA  = (u16*)take(128 * GE2 * 2);
  u16* gw1nA  = (u16*)take(128 * GN1 * 2);
  u16* gw2nA  = (u16*)take(128 * GN2 * 2);
  u16* gw1eB  = (u16*)take(128 * GE1 * 2);
  u16* gw2eB  = (u16*)take(128 * GE2 * 2);
  u16* gmweB  = (u16*)take(128 * GE2 * 2);
  u16* gw1nB  = (u16*)take(128 * GN1 * 2);
  u16* gw2nB  = (u16*)take(128 * GN2 * 2);

  const int EB = (NEDGES + 255) / 256;
  const int NB = (NNODES + 255) / 256;

  // stage all weights (bf16, transposed)
  stage_weights<<<dim3(16, 5), 256, 0, stream>>>(
      c2h_g_w1, c2h_g_w2, c2h_m_w, h_u_w1, h_u_w2,
      gw1eA, gw2eA, gmweA, gw1nA, gw2nA);
  stage_weights<<<dim3(16, 5), 256, 0, stream>>>(
      h2c_g_w1, h2c_g_w2, h2c_m_w, c_u_w1, c_u_w2,
      gw1eB, gw2eB, gmweB, gw1nB, gw2nB);

  // CSR build (both directions, fused; fill writes packed descriptors)
  hipMemsetAsync(cntA, 0, (size_t)NNODES * 2 * 4, stream);
  count2_k<<<EB, 256, 0, stream>>>(edges, cntA, cntB);
  scanA2_k<<<dim3(NCHUNK, 2), CHUNK, 0, stream>>>(cntA, cntB, offA, offB, csumA, csumB);
  scanB2_k<<<1, 64, 0, stream>>>(csumA, csumB);
  scanC2_k<<<dim3(NB, 2), 256, 0, stream>>>(offA, offB, posA, posB, csumA, csumB);
  fill2_k<<<EB, 256, 0, stream>>>(edges, posA, posB, pairA, pairB);

  // Phase 1: clue -> hidden. pairB is src(clue)-sorted; dstSlot -> CSR-A.
  edge_msg_w<<<256, 512, 0, stream>>>(h_clue, pairB, eattr,
      gw1eA, c2h_g_b1, gw2eA, c2h_g_b2, gmweA, c2h_m_b, msgs);
  node_csr<<<256, 512, 0, stream>>>(h_hidden, msgs, offA,
      gw1nA, h_u_b1, gw2nA, h_u_b2, h_ln_g, h_ln_b, out_hidden);

  // Phase 2: hidden_new -> clue. pairA is src(hidden)-sorted; dstSlot -> CSR-B.
  edge_msg_w<<<256, 512, 0, stream>>>(out_hidden, pairA, eattr,
      gw1eB, h2c_g_b1, gw2eB, h2c_g_b2, gmweB, h2c_m_b, msgs);
  node_csr<<<256, 512, 0, stream>>>(h_clue, msgs, offB,
      gw1nB, c_u_b1, gw2nB, c_u_b2, c_ln_g, c_ln_b, out_clue);
}

// Round 21
// 489.393 us; speedup vs baseline: 2.6633x; 1.1242x over previous
//
#include <hip/hip_runtime.h>

#define HH 128
#define EAA 16
#define NNODES 100000
#define NEDGES 500000
#define NBATCH (NEDGES / 16)   // 31250 exact
#define NNB    (NNODES / 16)   // 6250 exact
#define CHUNK 512
#define NCHUNK ((NNODES + CHUNK - 1) / CHUNK)  // 196

// global transposed-weight row strides (elements, 16B-multiple)
#define GE1 160   // edge w1t: k in [0,160), real 144, pad zeroed
#define GE2 128
#define GN1 256
#define GN2 128
// edge-kernel LDS weight strides (bank-spread, r7/r19-verified)
#define LW1 168
#define LW2 136
// node-kernel LDS weight strides
#define LN1 264
#define LN2 136
#define NW 8      // waves per block
#define LROW 136  // merged rows/msg tile stride in u16 (272 B)
#define OTS 36    // node out-tile stride in f32 (144 B, 16B-aligned)

typedef unsigned int u32;
typedef unsigned short u16;
typedef __attribute__((ext_vector_type(8))) short bf16x8;
typedef __attribute__((ext_vector_type(4))) short s16x4;
typedef __attribute__((ext_vector_type(4))) float f32x4;

__device__ __forceinline__ float bf_lo(u32 v){ return __builtin_bit_cast(float, (u32)(v << 16)); }
__device__ __forceinline__ float bf_hi(u32 v){ return __builtin_bit_cast(float, (u32)(v & 0xffff0000u)); }
__device__ __forceinline__ u16 f2bf(float f){
  u32 x = __builtin_bit_cast(u32, f);
  return (u16)((x + 0x7fffu + ((x >> 16) & 1u)) >> 16);
}
// fast sigmoid: v_rcp_f32 instead of the IEEE divide sequence (~1 ulp approx;
// output margin is 0.031 vs 0.11 threshold -> invisible)
__device__ __forceinline__ float sigm(float x){
  return __builtin_amdgcn_rcpf(1.0f + __expf(-x));
}
__device__ __forceinline__ uint2 shfl64(uint2 v, int src){
  uint2 r;
  r.x = (u32)__shfl((int)v.x, src, 64);
  r.y = (u32)__shfl((int)v.y, src, 64);
  return r;
}
__device__ __forceinline__ bf16x8 ld8f_bf(const float* p){
  float4 v0 = *(const float4*)(p);
  float4 v1 = *(const float4*)(p + 4);
  uint4 u;
  u.x = ((u32)f2bf(v0.y) << 16) | f2bf(v0.x);
  u.y = ((u32)f2bf(v0.w) << 16) | f2bf(v0.z);
  u.z = ((u32)f2bf(v1.y) << 16) | f2bf(v1.x);
  u.w = ((u32)f2bf(v1.w) << 16) | f2bf(v1.z);
  return __builtin_bit_cast(bf16x8, u);
}

// ===========================================================================
// Weight staging: transpose f32 [K][128] -> bf16 [128][Kpad] (zero pad).
// ===========================================================================
__global__ void stage_weights(
    const float* __restrict__ w1e, const float* __restrict__ w2e, const float* __restrict__ mwe,
    const float* __restrict__ w1n, const float* __restrict__ w2n,
    u16* __restrict__ gw1e, u16* __restrict__ gw2e, u16* __restrict__ gmwe,
    u16* __restrict__ gw1n, u16* __restrict__ gw2n)
{
  const float* src; u16* dst; int K, KP;
  switch (blockIdx.y) {
    case 0: src = w1e; dst = gw1e; K = 144; KP = GE1; break;
    case 1: src = w2e; dst = gw2e; K = 128; KP = GE2; break;
    case 2: src = mwe; dst = gmwe; K = 128; KP = GE2; break;
    case 3: src = w1n; dst = gw1n; K = 256; KP = GN1; break;
    default: src = w2n; dst = gw2n; K = 128; KP = GN2; break;
  }
  int total = 128 * KP;
  for (int i = blockIdx.x * blockDim.x + threadIdx.x; i < total; i += gridDim.x * blockDim.x) {
    int f = i / KP, k = i - f * KP;
    dst[i] = (k < K) ? f2bf(src[(size_t)k * 128 + f]) : (u16)0;
  }
}

// ===========================================================================
// CSR build (both directions fused): count -> scan -> fill.
// fill writes packed per-slot descriptors {src, dstSlot, eid}.
// ===========================================================================
__global__ void count2_k(const int* __restrict__ edges,
                         int* __restrict__ cntA, int* __restrict__ cntB){
  int e = blockIdx.x * blockDim.x + threadIdx.x;
  if (e < NEDGES){
    int2 p = ((const int2*)edges)[e];
    atomicAdd(&cntA[p.y], 1);
    atomicAdd(&cntB[p.x], 1);
  }
}
__global__ void scanA2_k(const int* __restrict__ cntA, const int* __restrict__ cntB,
                         int* __restrict__ offA, int* __restrict__ offB,
                         int* __restrict__ csumA, int* __restrict__ csumB){
  const int* cnt = blockIdx.y ? cntB : cntA;
  int* off  = blockIdx.y ? offB : offA;
  int* csum = blockIdx.y ? csumB : csumA;
  __shared__ int ws[8];
  int i = blockIdx.x * CHUNK + threadIdx.x;
  int v = (i < NNODES) ? cnt[i] : 0;
  int lane = threadIdx.x & 63, w = threadIdx.x >> 6;
  int s = v;
#pragma unroll
  for (int d = 1; d < 64; d <<= 1){ int t = __shfl_up(s, d, 64); if (lane >= d) s += t; }
  if (lane == 63) ws[w] = s;
  __syncthreads();
  if (threadIdx.x == 0){
    int a = 0;
    for (int k = 0; k < 8; k++){ int t = ws[k]; ws[k] = a; a += t; }
    csum[blockIdx.x] = a;
  }
  __syncthreads();
  if (i < NNODES) off[i] = (s - v) + ws[w];
}
__global__ void scanB2_k(int* __restrict__ csumA, int* __restrict__ csumB){
  int lane = threadIdx.x & 63;
  for (int which = 0; which < 2; which++){
    int* c = which ? csumB : csumA;
    int carry = 0;
    for (int base = 0; base < NCHUNK; base += 64){
      int idx = base + lane;
      int v = (idx < NCHUNK) ? c[idx] : 0;
      int s = v;
#pragma unroll
      for (int d = 1; d < 64; d <<= 1){ int t = __shfl_up(s, d, 64); if (lane >= d) s += t; }
      if (idx < NCHUNK) c[idx] = s - v + carry;
      carry += __shfl(s, 63, 64);
    }
  }
}
__global__ void scanC2_k(int* __restrict__ offA, int* __restrict__ offB,
                         int* __restrict__ posA, int* __restrict__ posB,
                         const int* __restrict__ csumA, const int* __restrict__ csumB){
  int* off = blockIdx.y ? offB : offA;
  int* pos = blockIdx.y ? posB : posA;
  const int* csum = blockIdx.y ? csumB : csumA;
  int i = blockIdx.x * blockDim.x + threadIdx.x;
  if (i < NNODES){ int v = off[i] + csum[i / CHUNK]; off[i] = v; pos[i] = v; }
  if (i == 0) off[NNODES] = NEDGES;
}
__global__ void fill2_k(const int* __restrict__ edges,
                        int* __restrict__ posA, int* __restrict__ posB,
                        int4* __restrict__ pairA, int4* __restrict__ pairB){
  int e = blockIdx.x * blockDim.x + threadIdx.x;
  if (e < NEDGES){
    int2 p = ((const int2*)edges)[e];
    int pa = atomicAdd(&posA[p.y], 1);
    int pb = atomicAdd(&posB[p.x], 1);
    pairA[pa] = make_int4(p.y, pb, e, 0);   // phase 2: src = hidden (col 1)
    pairB[pb] = make_int4(p.x, pa, e, 0);   // phase 1: src = clue (col 0)
  }
}

// ===========================================================================
// Edge message kernel — ROUND-20 VERIFIED FORM (weights in LDS, merged tile,
// descriptor loads, SRC-sorted, scatter to dst-CSR slot) + fast sigmoid.
// ===========================================================================
__global__ __launch_bounds__(512, 2) void edge_msg_w(
    const float* __restrict__ srcN,
    const int4* __restrict__ pair,
    const float* __restrict__ eattr,
    const u16* __restrict__ w1t, const float* __restrict__ b1,
    const u16* __restrict__ w2t, const float* __restrict__ b2,
    const u16* __restrict__ mwt, const float* __restrict__ mb,
    u16* __restrict__ msgs)
{
  __shared__ float b1s[HH], b2s[HH], mbs[HH];                 //  1536 B
  __shared__ alignas(16) u16 w1s[128 * LW1];                  // 43008 B
  __shared__ alignas(16) u16 w2s[128 * LW2];                  // 34816 B
  __shared__ alignas(16) u16 mws[128 * LW2];                  // 34816 B
  __shared__ alignas(16) u16 tile[NW][16 * LROW];             // 34816 B => 148992
  const int tid = threadIdx.x;
  if (tid < HH){ b1s[tid] = b1[tid]; b2s[tid] = b2[tid]; mbs[tid] = mb[tid]; }
  for (int i = tid; i < 128 * 20; i += 512) {        // w1: 160 u16/row = 20 uint4
    int r = i / 20, c = i - r * 20;
    ((uint4*)(w1s + r * LW1))[c] = ((const uint4*)(w1t + (size_t)r * GE1))[c];
  }
  for (int i = tid; i < 128 * 16; i += 512) {        // w2/mw: 16 uint4/row
    int r = i >> 4, c = i & 15;
    ((uint4*)(w2s + r * LW2))[c] = ((const uint4*)(w2t + (size_t)r * GE2))[c];
    ((uint4*)(mws + r * LW2))[c] = ((const uint4*)(mwt + (size_t)r * GE2))[c];
  }
  __syncthreads();

  const int lane = tid & 63;
  const int wid  = tid >> 6;
  const int q    = lane >> 4;
  const int er   = lane & 15;
  const int ll   = lane & 31;
  const int half = lane >> 5;
  const int gw   = blockIdx.x * NW + wid;
  const int nwv  = gridDim.x * NW;
  const int srcA = 2 * (q & 1) * 16 + er;
  const int srcB = srcA + 16;
  const bool hiT = (q >> 1) != 0;
  u16* mytile = tile[wid];

  for (int b = gw; b < NBATCH; b += nwv) {
    const int e0 = b * 16;
    int4 pr = pair[e0 + er];
    const int s   = pr.x;
    const int dp  = pr.y;
    const int eid = pr.z;

    // ---- coalesced gather: half-wave loads one full 512-B row, bf16 -> LDS
#pragma unroll
    for (int p = 0; p < 8; p++) {
      int j = 2 * p + half;
      int sj = __shfl(s, j, 64);
      float4 v = *(const float4*)(srcN + (size_t)sj * HH + ll * 4);
      uint2 pk;
      pk.x = ((u32)f2bf(v.y) << 16) | f2bf(v.x);
      pk.y = ((u32)f2bf(v.w) << 16) | f2bf(v.z);
      *(s16x4*)(mytile + j * LROW + ll * 4) = __builtin_bit_cast(s16x4, pk);
    }
    asm volatile("" ::: "memory");

    // ---- B-frags from LDS + eattr tail
    bf16x8 bs[5];
#pragma unroll
    for (int kt = 0; kt < 4; kt++)
      bs[kt] = *(const bf16x8*)(mytile + er * LROW + kt * 32 + q * 8);
    if (q < 2) bs[4] = ld8f_bf(eattr + (size_t)eid * EAA + q * 8);
    else       bs[4] = (bf16x8){0,0,0,0,0,0,0,0};
    asm volatile("" ::: "memory");

    // ---- stage 1: y^T + SiLU (A-frags from LDS)
    uint2 pku[8];
#pragma unroll
    for (int t = 0; t < 8; t++) {
      const u16* ap = w1s + (t * 16 + er) * LW1 + q * 8;
      f32x4 acc = {b1s[t*16 + q*4 + 0], b1s[t*16 + q*4 + 1],
                   b1s[t*16 + q*4 + 2], b1s[t*16 + q*4 + 3]};
#pragma unroll
      for (int kt = 0; kt < 5; kt++) {
        bf16x8 af = *(const bf16x8*)(ap + kt * 32);
        acc = __builtin_amdgcn_mfma_f32_16x16x32_bf16(af, bs[kt], acc, 0, 0, 0);
      }
      float v0 = acc[0] * sigm(acc[0]), v1 = acc[1] * sigm(acc[1]);
      float v2 = acc[2] * sigm(acc[2]), v3 = acc[3] * sigm(acc[3]);
      pku[t].x = ((u32)f2bf(v1) << 16) | f2bf(v0);
      pku[t].y = ((u32)f2bf(v3) << 16) | f2bf(v2);
    }

    // ---- D-layout -> B-frag redistribution (in-register)
    bf16x8 yb[4];
#pragma unroll
    for (int kt = 0; kt < 4; kt++) {
      uint2 aLo = shfl64(pku[2*kt],     srcA);
      uint2 aHi = shfl64(pku[2*kt + 1], srcA);
      uint2 bLo = shfl64(pku[2*kt],     srcB);
      uint2 bHi = shfl64(pku[2*kt + 1], srcB);
      uint4 w;
      w.x = hiT ? aHi.x : aLo.x;
      w.y = hiT ? aHi.y : aLo.y;
      w.z = hiT ? bHi.x : bLo.x;
      w.w = hiT ? bHi.y : bLo.y;
      yb[kt] = __builtin_bit_cast(bf16x8, w);
    }

    // ---- stage 2+3: gate & message -> merged tile (WAR-safe)
#pragma unroll
    for (int t = 0; t < 8; t++) {
      const u16* ap2 = w2s + (t * 16 + er) * LW2 + q * 8;
      const u16* ap3 = mws + (t * 16 + er) * LW2 + q * 8;
      f32x4 g = {b2s[t*16 + q*4 + 0], b2s[t*16 + q*4 + 1],
                 b2s[t*16 + q*4 + 2], b2s[t*16 + q*4 + 3]};
      f32x4 m = {mbs[t*16 + q*4 + 0], mbs[t*16 + q*4 + 1],
                 mbs[t*16 + q*4 + 2], mbs[t*16 + q*4 + 3]};
#pragma unroll
      for (int kt = 0; kt < 4; kt++) {
        bf16x8 a2 = *(const bf16x8*)(ap2 + kt * 32);
        g = __builtin_amdgcn_mfma_f32_16x16x32_bf16(a2, yb[kt], g, 0, 0, 0);
        bf16x8 a3 = *(const bf16x8*)(ap3 + kt * 32);
        m = __builtin_amdgcn_mfma_f32_16x16x32_bf16(a3, bs[kt], m, 0, 0, 0);
      }
      float v0 = m[0] * sigm(g[0]), v1 = m[1] * sigm(g[1]);
      float v2 = m[2] * sigm(g[2]), v3 = m[3] * sigm(g[3]);
      uint2 pk;
      pk.x = ((u32)f2bf(v1) << 16) | f2bf(v0);
      pk.y = ((u32)f2bf(v3) << 16) | f2bf(v2);
      *(s16x4*)(mytile + er * LROW + t * 16 + q * 4) = __builtin_bit_cast(s16x4, pk);
    }
    asm volatile("" ::: "memory");

    // ---- scatter store: quarter-wave per edge, 256 B = 2 full lines
#pragma unroll
    for (int p = 0; p < 4; p++) {
      int e_r = 4 * p + q;
      int dslot = __shfl(dp, e_r, 64);
      bf16x8 v = *(const bf16x8*)(mytile + e_r * LROW + er * 8);
      *(bf16x8*)(msgs + (size_t)dslot * 128 + er * 8) = v;
    }
    asm volatile("" ::: "memory");
  }
}

// ===========================================================================
// Node update — ROUND-20 VERIFIED FORM (weights in LDS, CSR pull-agg,
// full-line out stores). Byte-identical to round 20.
// ===========================================================================
__global__ __launch_bounds__(512, 2) void node_csr(
    const float* __restrict__ hin,
    const u16* __restrict__ msgs, const int* __restrict__ off,
    const u16* __restrict__ w1t, const float* __restrict__ b1,
    const u16* __restrict__ w2t, const float* __restrict__ b2,
    const float* __restrict__ lng, const float* __restrict__ lnb,
    float* __restrict__ out)
{
  __shared__ float b1s[HH], b2s[HH], gsv[HH], bsv[HH];        //  2048 B
  __shared__ alignas(16) u16 w1s[128 * LN1];                  // 67584 B
  __shared__ alignas(16) u16 w2s[128 * LN2];                  // 34816 B
  __shared__ alignas(16) float otile[NW][16 * OTS];           // 18432 B => 122880
  const int tid = threadIdx.x;
  if (tid < HH){ b1s[tid] = b1[tid]; b2s[tid] = b2[tid];
                 gsv[tid] = lng[tid]; bsv[tid] = lnb[tid]; }
  for (int i = tid; i < 128 * 32; i += 512) {        // w1: 32 uint4/row
    int r = i >> 5, c = i & 31;
    ((uint4*)(w1s + r * LN1))[c] = ((const uint4*)(w1t + (size_t)r * GN1))[c];
  }
  for (int i = tid; i < 128 * 16; i += 512) {        // w2: 16 uint4/row
    int r = i >> 4, c = i & 15;
    ((uint4*)(w2s + r * LN2))[c] = ((const uint4*)(w2t + (size_t)r * GN2))[c];
  }
  __syncthreads();

  const int lane = tid & 63;
  const int wid  = tid >> 6;
  const int q    = lane >> 4;
  const int nr   = lane & 15;
  const int gw   = blockIdx.x * NW + wid;
  const int nwv  = gridDim.x * NW;
  const int srcA = 2 * (q & 1) * 16 + nr;
  const int srcB = srcA + 16;
  const bool hiT = (q >> 1) != 0;
  float* myot = otile[wid];

  for (int nb = gw; nb < NNB; nb += nwv) {
    const int n = nb * 16 + nr;
    const size_t base = (size_t)n * HH;

    // ---- pull-aggregate: contiguous CSR slots of this node
    float av[32];
#pragma unroll
    for (int j = 0; j < 32; j++) av[j] = 0.0f;
    const int beg = off[n], end = off[n + 1];
    for (int i = 0; ; i++) {
      bool act = (beg + i < end);
      if (!__any(act)) break;
      if (act) {
        const u16* mp = msgs + (size_t)(beg + i) * 128 + q * 8;
#pragma unroll
        for (int kt = 0; kt < 4; kt++) {
          uint4 r = *(const uint4*)(mp + kt * 32);
          av[kt*8+0] += bf_lo(r.x); av[kt*8+1] += bf_hi(r.x);
          av[kt*8+2] += bf_lo(r.y); av[kt*8+3] += bf_hi(r.y);
          av[kt*8+4] += bf_lo(r.z); av[kt*8+5] += bf_hi(r.z);
          av[kt*8+6] += bf_lo(r.w); av[kt*8+7] += bf_hi(r.w);
        }
      }
    }

    // ---- B-frags: cat = [hin | agg]
    bf16x8 cb[8];
    const float* hp = hin + base + q * 8;
    cb[0] = ld8f_bf(hp);
    cb[1] = ld8f_bf(hp + 32);
    cb[2] = ld8f_bf(hp + 64);
    cb[3] = ld8f_bf(hp + 96);
#pragma unroll
    for (int kt = 0; kt < 4; kt++) {
      uint4 u;
      u.x = ((u32)f2bf(av[kt*8+1]) << 16) | f2bf(av[kt*8+0]);
      u.y = ((u32)f2bf(av[kt*8+3]) << 16) | f2bf(av[kt*8+2]);
      u.z = ((u32)f2bf(av[kt*8+5]) << 16) | f2bf(av[kt*8+4]);
      u.w = ((u32)f2bf(av[kt*8+7]) << 16) | f2bf(av[kt*8+6]);
      cb[4 + kt] = __builtin_bit_cast(bf16x8, u);
    }

    // ---- stage 1: u^T = relu(w1^T @ cat^T + b1)  (A-frags from LDS)
    uint2 pku[8];
#pragma unroll
    for (int t = 0; t < 8; t++) {
      const u16* a1p = w1s + (t * 16 + nr) * LN1 + q * 8;
      f32x4 acc = {b1s[t*16 + q*4 + 0], b1s[t*16 + q*4 + 1],
                   b1s[t*16 + q*4 + 2], b1s[t*16 + q*4 + 3]};
#pragma unroll
      for (int kt = 0; kt < 8; kt++) {
        bf16x8 af = *(const bf16x8*)(a1p + kt * 32);
        acc = __builtin_amdgcn_mfma_f32_16x16x32_bf16(af, cb[kt], acc, 0, 0, 0);
      }
      float v0 = fmaxf(acc[0], 0.0f), v1 = fmaxf(acc[1], 0.0f);
      float v2 = fmaxf(acc[2], 0.0f), v3 = fmaxf(acc[3], 0.0f);
      pku[t].x = ((u32)f2bf(v1) << 16) | f2bf(v0);
      pku[t].y = ((u32)f2bf(v3) << 16) | f2bf(v2);
    }

    bf16x8 yb[4];
#pragma unroll
    for (int kt = 0; kt < 4; kt++) {
      uint2 aLo = shfl64(pku[2*kt],     srcA);
      uint2 aHi = shfl64(pku[2*kt + 1], srcA);
      uint2 bLo = shfl64(pku[2*kt],     srcB);
      uint2 bHi = shfl64(pku[2*kt + 1], srcB);
      uint4 w;
      w.x = hiT ? aHi.x : aLo.x;
      w.y = hiT ? aHi.y : aLo.y;
      w.z = hiT ? bHi.x : bLo.x;
      w.w = hiT ? bHi.y : bLo.y;
      yb[kt] = __builtin_bit_cast(bf16x8, w);
    }

    // ---- stage 2 + residual + LN  (A-frags from LDS)
    float xv[8][4];
    float psum = 0.0f;
#pragma unroll
    for (int t = 0; t < 8; t++) {
      const u16* a2p = w2s + (t * 16 + nr) * LN2 + q * 8;
      f32x4 uacc = {b2s[t*16 + q*4 + 0], b2s[t*16 + q*4 + 1],
                    b2s[t*16 + q*4 + 2], b2s[t*16 + q*4 + 3]};
#pragma unroll
      for (int kt = 0; kt < 4; kt++) {
        bf16x8 a2 = *(const bf16x8*)(a2p + kt * 32);
        uacc = __builtin_amdgcn_mfma_f32_16x16x32_bf16(a2, yb[kt], uacc, 0, 0, 0);
      }
      float4 hv = *(const float4*)(hin + base + t * 16 + q * 4);
      xv[t][0] = hv.x + uacc[0];
      xv[t][1] = hv.y + uacc[1];
      xv[t][2] = hv.z + uacc[2];
      xv[t][3] = hv.w + uacc[3];
      psum += xv[t][0] + xv[t][1] + xv[t][2] + xv[t][3];
    }
    psum += __shfl_xor(psum, 16, 64);
    psum += __shfl_xor(psum, 32, 64);
    float mu = psum * (1.0f / 128.0f);
    float pvar = 0.0f;
#pragma unroll
    for (int t = 0; t < 8; t++) {
#pragma unroll
      for (int j = 0; j < 4; j++) {
        float dx = xv[t][j] - mu;
        xv[t][j] = dx;
        pvar += dx * dx;
      }
    }
    pvar += __shfl_xor(pvar, 16, 64);
    pvar += __shfl_xor(pvar, 32, 64);
    float inv = rsqrtf(pvar * (1.0f / 128.0f) + 1e-5f);
#pragma unroll
    for (int t = 0; t < 8; t++) {
      int F = t * 16 + q * 4;
      xv[t][0] = xv[t][0] * inv * gsv[F + 0] + bsv[F + 0];
      xv[t][1] = xv[t][1] * inv * gsv[F + 1] + bsv[F + 1];
      xv[t][2] = xv[t][2] * inv * gsv[F + 2] + bsv[F + 2];
      xv[t][3] = xv[t][3] * inv * gsv[F + 3] + bsv[F + 3];
    }

    // ---- full-line out stores via LDS transpose tile.
#pragma unroll
    for (int tp = 0; tp < 4; tp++) {
      asm volatile("" ::: "memory");
#pragma unroll
      for (int dt = 0; dt < 2; dt++) {
        int t = 2 * tp + dt;
        float4 v; v.x = xv[t][0]; v.y = xv[t][1]; v.z = xv[t][2]; v.w = xv[t][3];
        *(float4*)(myot + nr * OTS + dt * 16 + q * 4) = v;
      }
      asm volatile("" ::: "memory");
#pragma unroll
      for (int hf = 0; hf < 2; hf++) {
        int n8 = hf * 8 + (lane >> 3);
        int f  = (lane & 7) * 4;
        float4 v = *(const float4*)(myot + n8 * OTS + f);
        *(float4*)(out + (size_t)(nb * 16 + n8) * HH + tp * 32 + f) = v;
      }
    }
  }
}

// ===========================================================================
extern "C" void kernel_launch(void* const* d_in, const int* in_sizes, int n_in,
                              void* d_out, int out_size, void* d_ws, size_t ws_size,
                              hipStream_t stream) {
  const float* h_hidden = (const float*)d_in[0];
  const float* h_clue   = (const float*)d_in[1];
  const int*   edges    = (const int*)d_in[2];
  const float* eattr    = (const float*)d_in[3];
  const float* c2h_g_w1 = (const float*)d_in[4];  const float* c2h_g_b1 = (const float*)d_in[5];
  const float* c2h_g_w2 = (const float*)d_in[6];  const float* c2h_g_b2 = (const float*)d_in[7];
  const float* c2h_m_w  = (const float*)d_in[8];  const float* c2h_m_b  = (const float*)d_in[9];
  const float* h_u_w1   = (const float*)d_in[10]; const float* h_u_b1   = (const float*)d_in[11];
  const float* h_u_w2   = (const float*)d_in[12]; const float* h_u_b2   = (const float*)d_in[13];
  const float* h_ln_g   = (const float*)d_in[14]; const float* h_ln_b   = (const float*)d_in[15];
  const float* h2c_g_w1 = (const float*)d_in[16]; const float* h2c_g_b1 = (const float*)d_in[17];
  const float* h2c_g_w2 = (const float*)d_in[18]; const float* h2c_g_b2 = (const float*)d_in[19];
  const float* h2c_m_w  = (const float*)d_in[20]; const float* h2c_m_b  = (const float*)d_in[21];
  const float* c_u_w1   = (const float*)d_in[22]; const float* c_u_b1   = (const float*)d_in[23];
  const float* c_u_w2   = (const float*)d_in[24]; const float* c_u_b2   = (const float*)d_in[25];
  const float* c_ln_g   = (const float*)d_in[26]; const float* c_ln_b   = (const float*)d_in[27];

  float* out_hidden = (float*)d_out;
  float* out_clue   = (float*)d_out + (size_t)NNODES * HH;

  // ---- workspace carve-up
  char* W = (char*)d_ws;
  size_t woff = 0;
  auto take = [&](size_t nbytes) -> char* {
    char* p = W + woff;
    woff += (nbytes + 255) & ~(size_t)255;
    return p;
  };
  u16*  msgs  = (u16*)take((size_t)NEDGES * HH * 2);       // 128 MB
  int*  cntA  = (int*)take((size_t)NNODES * 2 * 4);        // contiguous pair
  int*  cntB  = cntA + NNODES;
  int*  offA  = (int*)take((size_t)(NNODES + 1) * 4);
  int*  offB  = (int*)take((size_t)(NNODES + 1) * 4);
  int*  posA  = (int*)take((size_t)NNODES * 4);
  int*  posB  = (int*)take((size_t)NNODES * 4);
  int4* pairA = (int4*)take((size_t)NEDGES * 16);          // 8 MB
  int4* pairB = (int4*)take((size_t)NEDGES * 16);          // 8 MB
  int*  csumA = (int*)take((size_t)NCHUNK * 4);
  int*  csumB = (int*)take((size_t)NCHUNK * 4);
  u16* gw1eA  = (u16*)take(128 * GE1 * 2);
  u16* gw2eA  = (u16*)take(128 * GE2 * 2);
  u16* gmweA  = (u16*)take(128 * GE2 * 2);
  u16* gw1nA  = (u16*)take(128 * GN1 * 2);
  u16* gw2nA  = (u16*)take(128 * GN2 * 2);
  u16* gw1eB  = (u16*)take(128 * GE1 * 2);
  u16* gw2eB  = (u16*)take(128 * GE2 * 2);
  u16* gmweB  = (u16*)take(128 * GE2 * 2);
  u16* gw1nB  = (u16*)take(128 * GN1 * 2);
  u16* gw2nB  = (u16*)take(128 * GN2 * 2);

  const int EB = (NEDGES + 255) / 256;
  const int NB = (NNODES + 255) / 256;

  // stage all weights (bf16, transposed)
  stage_weights<<<dim3(16, 5), 256, 0, stream>>>(
      c2h_g_w1, c2h_g_w2, c2h_m_w, h_u_w1, h_u_w2,
      gw1eA, gw2eA, gmweA, gw1nA, gw2nA);
  stage_weights<<<dim3(16, 5), 256, 0, stream>>>(
      h2c_g_w1, h2c_g_w2, h2c_m_w, c_u_w1, c_u_w2,
      gw1eB, gw2eB, gmweB, gw1nB, gw2nB);

  // CSR build (both directions, fused; fill writes packed descriptors)
  hipMemsetAsync(cntA, 0, (size_t)NNODES * 2 * 4, stream);
  count2_k<<<EB, 256, 0, stream>>>(edges, cntA, cntB);
  scanA2_k<<<dim3(NCHUNK, 2), CHUNK, 0, stream>>>(cntA, cntB, offA, offB, csumA, csumB);
  scanB2_k<<<1, 64, 0, stream>>>(csumA, csumB);
  scanC2_k<<<dim3(NB, 2), 256, 0, stream>>>(offA, offB, posA, posB, csumA, csumB);
  fill2_k<<<EB, 256, 0, stream>>>(edges, posA, posB, pairA, pairB);

  // Phase 1: clue -> hidden. pairB is src(clue)-sorted; dstSlot -> CSR-A.
  edge_msg_w<<<256, 512, 0, stream>>>(h_clue, pairB, eattr,
      gw1eA, c2h_g_b1, gw2eA, c2h_g_b2, gmweA, c2h_m_b, msgs);
  node_csr<<<256, 512, 0, stream>>>(h_hidden, msgs, offA,
      gw1nA, h_u_b1, gw2nA, h_u_b2, h_ln_g, h_ln_b, out_hidden);

  // Phase 2: hidden_new -> clue. pairA is src(hidden)-sorted; dstSlot -> CSR-B.
  edge_msg_w<<<256, 512, 0, stream>>>(out_hidden, pairA, eattr,
      gw1eB, h2c_g_b1, gw2eB, h2c_g_b2, gmweB, h2c_m_b, msgs);
  node_csr<<<256, 512, 0, stream>>>(h_clue, msgs, offB,
      gw1nB, c_u_b1, gw2nB, c_u_b2, c_ln_g, c_ln_b, out_clue);
}